// Round 1
// baseline (6389.516 us; speedup 1.0000x reference)
//
#include <hip/hip_runtime.h>
#include <hip/hip_fp16.h>

// Persistent-kernel autoregressive LSTM for MI355X (gfx950).
//
// Structure: 100 steps x 3 grid-barrier windows (L1 / L2 / L3). The decoder is
// folded off the critical path via W_eff = W_ih1 @ dec_w (precomputed per call),
// and out(t-1) is computed opportunistically during window A of step t.
// Activations: fp16, rotating buffers (fresh addresses each step -> no stale-L2
// hazard), written with agent-scope (device-coherent) stores. Weights: fp16,
// MFMA-B-fragment packed, streamed through L2/L3 (never invalidated).
// MFMA: v_mfma_f32_16x16x32_f16, fp32 accumulate.

typedef unsigned short u16;
typedef unsigned int u32;
typedef _Float16 f16;
typedef _Float16 h8 __attribute__((ext_vector_type(8)));
typedef float f4 __attribute__((ext_vector_type(4)));

#define HSZ 65536  // halves per h slot: 64 batch x 1024 hidden

static __device__ __forceinline__ f4 mfma16(h8 a, h8 b, f4 c) {
  return __builtin_amdgcn_mfma_f32_16x16x32_f16(a, b, c, 0, 0, 0);
}

// A-frag: lane holds A[m=lane&15][k=(lane>>4)*8 + j]  (activations, row-major)
// B-frag: lane holds W[n=lane&15][k=(lane>>4)*8 + j]  (weights, pre-packed)
// D:      lane holds D[row=(lane>>4)*4+reg][col=lane&15]
template<int NKT, int RS>
static __device__ __forceinline__ void gemm_sect(f4& acc, const u16* __restrict__ hbase,
                                                 const u16* __restrict__ wbase,
                                                 int wv, int m, int q, int lane) {
  const u16* ap = hbase + (size_t)(wv * 16 + m) * RS + q * 8;
  const u16* bp = wbase + lane * 8;
#pragma unroll
  for (int kt = 0; kt < NKT; ++kt) {
    h8 a = *(const h8*)(ap + kt * 32);
    h8 b = *(const h8*)(bp + (size_t)kt * 512);
    acc = mfma16(a, b, acc);
  }
}

struct P {
  const u16 *w1h, *weff, *w1x, *w2, *w3, *wdec, *fr;
  const float *br, *ba, *b2s, *b3s, *dec_b;
  u16 *h0, *h1, *h2;
  float* out;
  u32* bar;
};

__launch_bounds__(256, 1)
__global__ void lstm_main(P p) {
  const int ng = blockIdx.x;        // unit-group: owns hidden units [4*ng, 4*ng+4)
  const int tid = threadIdx.x;
  const int lane = tid & 63;
  const int wv = tid >> 6;          // wave = batch tile (16 rows each)
  const int c = lane & 15;          // D column: gate = c>>2, unit = c&3
  const int q = lane >> 4;
  const int m = c;                  // A-frag row within batch tile

  __shared__ float gb[4][16][16];   // [batch-tile][batch row][col] post-nonlin gates
  __shared__ float cst[3][64][4];   // persistent c state [layer][batch][unit]
  __shared__ float decp[4][64];     // decoder partials

  for (int i = tid; i < 3 * 64 * 4; i += 256) ((float*)cst)[i] = 0.f;

  const int gate = c >> 2;
  const bool isg = (gate == 2);
  const int bias_idx = gate * 1024 + ng * 4 + (c & 3);
  u32 bidx = 0;

  auto nonlin_to_lds = [&](f4 acc, float bs) {
#pragma unroll
    for (int r = 0; r < 4; ++r) {
      float pre = acc[r] + bs;
      float v = isg ? tanhf(pre) : 1.f / (1.f + __expf(-pre));
      gb[wv][q * 4 + r][c] = v;
    }
  };

  auto combine = [&](int L, u16* hw) {
    if (tid < 128) {
      int b = tid >> 1, up = tid & 1;
      int bt = b >> 4, mm = b & 15;
      u32 pk = 0;
#pragma unroll
      for (int e = 0; e < 2; ++e) {
        int u = up * 2 + e;
        float iv = gb[bt][mm][0 + u];
        float fv = gb[bt][mm][4 + u];
        float gv = gb[bt][mm][8 + u];
        float ov = gb[bt][mm][12 + u];
        float cn = fv * cst[L][b][u] + iv * gv;
        cst[L][b][u] = cn;
        f16 hh = (f16)(ov * tanhf(cn));
        pk |= ((u32)*(u16*)&hh) << (16 * e);
      }
      // agent-scope store: write-through to L3 so all XCDs see it after barrier
      u32* dst = (u32*)hw + (size_t)b * 512 + ng * 2 + up;
      __hip_atomic_store(dst, pk, __ATOMIC_RELAXED, __HIP_MEMORY_SCOPE_AGENT);
    }
  };

  auto gridbar = [&]() {
    __syncthreads();  // all threads' stores retired (s_waitcnt vmcnt(0) at barrier)
    if (tid == 0) {
      ++bidx;
      u32 a = __hip_atomic_fetch_add(p.bar + (ng & 7) * 32, 1u, __ATOMIC_RELAXED,
                                     __HIP_MEMORY_SCOPE_AGENT);
      if (a == bidx * 32 - 1) {  // last WG of this XCD group this round
        u32 g2 = __hip_atomic_fetch_add(p.bar + 320, 1u, __ATOMIC_RELAXED,
                                        __HIP_MEMORY_SCOPE_AGENT);
        if (g2 == bidx * 8 - 1)
          __hip_atomic_store(p.bar + 384, bidx, __ATOMIC_RELAXED, __HIP_MEMORY_SCOPE_AGENT);
      }
      while (__hip_atomic_load(p.bar + 384, __ATOMIC_RELAXED, __HIP_MEMORY_SCOPE_AGENT) < bidx)
        __builtin_amdgcn_s_sleep(1);
    }
    __syncthreads();
  };

  auto dec_partial = [&](const u16* h2base) {
    if (ng < 171) {
      int b = tid & 63, qq = tid >> 6;
      const u16* hp = h2base + b * 1024 + qq * 256;
      const u16* wp = p.wdec + ng * 1024 + qq * 256;
      float s = 0.f;
#pragma unroll 4
      for (int i = 0; i < 32; ++i) {
        h8 hv = *(const h8*)(hp + i * 8);
        h8 wv8 = *(const h8*)(wp + i * 8);
#pragma unroll
        for (int j = 0; j < 8; ++j) s += (float)hv[j] * (float)wv8[j];
      }
      decp[qq][b] = s;
    }
  };
  auto dec_reduce = [&](int tout) {
    if (ng < 171 && tid < 64) {
      float o = decp[0][tid] + decp[1][tid] + decp[2][tid] + decp[3][tid] + p.dec_b[ng];
      p.out[(size_t)tid * 17100 + (size_t)tout * 171 + ng] = o;
    }
  };

  for (int t = 0; t < 100; ++t) {
    const bool cond = (t % 10) < 5;
    const u16* h0r = p.h0 + (size_t)t * HSZ;       // h(t-1); slot 0 = zeros
    const u16* h1r = p.h1 + (size_t)t * HSZ;
    const u16* h2r = p.h2 + (size_t)t * HSZ;
    u16* h0w = p.h0 + (size_t)(t + 1) * HSZ;
    u16* h1w = p.h1 + (size_t)(t + 1) * HSZ;
    u16* h2w = p.h2 + (size_t)(t + 1) * HSZ;

    // ---- window A: layer 1 (+ decoder for t-1, off critical path) ----
    {
      f4 acc = {0.f, 0.f, 0.f, 0.f};
      gemm_sect<32, 1024>(acc, h0r, p.w1h + (size_t)ng * 32 * 512, wv, m, q, lane);
      if (cond)
        gemm_sect<6, 192>(acc, p.fr + (size_t)t * 64 * 192, p.w1x + (size_t)ng * 6 * 512,
                          wv, m, q, lane);
      else  // in_frame = out(t-1) folded: W_eff @ h2(t-1), bias_auto has W_ih1@dec_b
        gemm_sect<32, 1024>(acc, h2r, p.weff + (size_t)ng * 32 * 512, wv, m, q, lane);
      nonlin_to_lds(acc, (cond ? p.br : p.ba)[bias_idx]);
      if (t > 0) dec_partial(h2r);
      __syncthreads();
      combine(0, h0w);
      if (t > 0) dec_reduce(t - 1);
      gridbar();
    }
    // ---- window B: layer 2 ----
    {
      f4 acc = {0.f, 0.f, 0.f, 0.f};
      gemm_sect<32, 1024>(acc, h0w, p.w2 + (size_t)ng * 64 * 512, wv, m, q, lane);
      gemm_sect<32, 1024>(acc, h1r, p.w2 + ((size_t)ng * 64 + 32) * 512, wv, m, q, lane);
      nonlin_to_lds(acc, p.b2s[bias_idx]);
      __syncthreads();
      combine(1, h1w);
      gridbar();
    }
    // ---- window C: layer 3 ----
    {
      f4 acc = {0.f, 0.f, 0.f, 0.f};
      gemm_sect<32, 1024>(acc, h1w, p.w3 + (size_t)ng * 64 * 512, wv, m, q, lane);
      gemm_sect<32, 1024>(acc, h2r, p.w3 + ((size_t)ng * 64 + 32) * 512, wv, m, q, lane);
      nonlin_to_lds(acc, p.b3s[bias_idx]);
      __syncthreads();
      combine(2, h2w);
      gridbar();
    }
  }
  // final decoder: out(99) from h2(99) (slot 100), already visible after last barrier
  {
    dec_partial(p.h2 + (size_t)100 * HSZ);
    __syncthreads();
    dec_reduce(99);
  }
}

// ------------------------- prep kernels -------------------------

// Pack a [4096 x (KA+KB)] fp32 weight (two source halves) into MFMA-B fragments:
// dst[((ng*nkt + kt)*64 + lane)*8 + j] = W[row(c)][kt*32 + (lane>>4)*8 + j]
// row(c) = (c>>2)*1024 + ng*4 + (c&3), c = lane&15.  Zero-pads k >= KA+KB.
__global__ void pack_w_kernel(const float* __restrict__ srcA, int KA,
                              const float* __restrict__ srcB, int KB,
                              u16* __restrict__ dst, int nkt) {
  int blk = blockIdx.x;
  int ng = blk / nkt, kt = blk % nkt;
  int lane = threadIdx.x;
  int c = lane & 15, q = lane >> 4;
  int row = (c >> 2) * 1024 + ng * 4 + (c & 3);
  int k0 = kt * 32 + q * 8;
  alignas(16) u16 outv[8];
  for (int j = 0; j < 8; ++j) {
    int k = k0 + j;
    float v = 0.f;
    if (k < KA) v = srcA[(size_t)row * KA + k];
    else if (k - KA < KB) v = srcB[(size_t)row * KB + (k - KA)];
    f16 hv = (f16)v;
    outv[j] = *(u16*)&hv;
  }
  *(uint4*)(dst + ((size_t)blk * 64 + lane) * 8) = *(const uint4*)outv;
}

// W_eff[n][k] = sum_{r<171} w_ih1[n][r] * dec_w[r][k], written MFMA-B packed fp16.
__global__ void pack_weff_kernel(const float* __restrict__ w_ih1,
                                 const float* __restrict__ dec_w, u16* __restrict__ dst) {
  int blk = blockIdx.x;  // ng*32 + kt
  int ng = blk >> 5, kt = blk & 31;
  int lane = threadIdx.x;
  int c = lane & 15, q = lane >> 4;
  int row = (c >> 2) * 1024 + ng * 4 + (c & 3);
  int k0 = kt * 32 + q * 8;
  float acc[8] = {0.f, 0.f, 0.f, 0.f, 0.f, 0.f, 0.f, 0.f};
  for (int r = 0; r < 171; ++r) {
    float wi = w_ih1[(size_t)row * 171 + r];
    const float* dw = dec_w + (size_t)r * 1024 + k0;
#pragma unroll
    for (int j = 0; j < 8; ++j) acc[j] += wi * dw[j];
  }
  alignas(16) u16 outv[8];
  for (int j = 0; j < 8; ++j) { f16 hv = (f16)acc[j]; outv[j] = *(u16*)&hv; }
  *(uint4*)(dst + ((size_t)blk * 64 + lane) * 8) = *(const uint4*)outv;
}

__global__ void prep_bias_kernel(const float* b_ih1, const float* b_hh1,
                                 const float* w_ih1, const float* dec_b,
                                 const float* b_ih2, const float* b_hh2,
                                 const float* b_ih3, const float* b_hh3,
                                 float* br, float* ba, float* b2, float* b3) {
  int n = blockIdx.x * 256 + threadIdx.x;  // 0..4095
  float s = b_ih1[n] + b_hh1[n];
  br[n] = s;
  float a = 0.f;
  for (int r = 0; r < 171; ++r) a += w_ih1[(size_t)n * 171 + r] * dec_b[r];
  ba[n] = s + a;  // autoregressive path: + W_ih1 @ dec_b
  b2[n] = b_ih2[n] + b_hh2[n];
  b3[n] = b_ih3[n] + b_hh3[n];
}

// real_seq [64][100][171] fp32 -> fr16 [100][64][192] fp16 (zero-padded K)
__global__ void pack_frames_kernel(const float* __restrict__ rs, u16* __restrict__ fr) {
  int i = blockIdx.x * 256 + threadIdx.x;
  int j = i % 192;
  int tb = i / 192;
  int b = tb % 64, t = tb / 64;
  float v = (j < 171) ? rs[((size_t)b * 100 + t) * 171 + j] : 0.f;
  f16 hv = (f16)v;
  fr[i] = *(u16*)&hv;
}

__global__ void pack_wdec_kernel(const float* __restrict__ dw, u16* __restrict__ dst) {
  int i = blockIdx.x * 256 + threadIdx.x;
  if (i < 171 * 1024) { f16 hv = (f16)dw[i]; dst[i] = *(u16*)&hv; }
}

// zero h slot 0 of each buffer (initial state) and the barrier page
__global__ void zero_kernel(u32* h0, u32* h1, u32* h2, u32* bar) {
  int i = blockIdx.x * 256 + threadIdx.x;  // 0..32767
  h0[i] = 0; h1[i] = 0; h2[i] = 0;
  if (blockIdx.x == 0) {
    bar[threadIdx.x] = 0; bar[256 + threadIdx.x] = 0;
    bar[512 + threadIdx.x] = 0; bar[768 + threadIdx.x] = 0;
  }
}

extern "C" void kernel_launch(void* const* d_in, const int* in_sizes, int n_in,
                              void* d_out, int out_size, void* d_ws, size_t ws_size,
                              hipStream_t stream) {
  const float* real_seq = (const float*)d_in[0];
  const float* w_ih1 = (const float*)d_in[1];
  const float* w_hh1 = (const float*)d_in[2];
  const float* b_ih1 = (const float*)d_in[3];
  const float* b_hh1 = (const float*)d_in[4];
  const float* w_ih2 = (const float*)d_in[5];
  const float* w_hh2 = (const float*)d_in[6];
  const float* b_ih2 = (const float*)d_in[7];
  const float* b_hh2 = (const float*)d_in[8];
  const float* w_ih3 = (const float*)d_in[9];
  const float* w_hh3 = (const float*)d_in[10];
  const float* b_ih3 = (const float*)d_in[11];
  const float* b_hh3 = (const float*)d_in[12];
  const float* dec_w = (const float*)d_in[13];
  const float* dec_b = (const float*)d_in[14];

  char* ws = (char*)d_ws;
  size_t off = 0;
  auto alloc = [&](size_t bytes) {
    char* pp = ws + off;
    off += (bytes + 255) & ~(size_t)255;
    return pp;
  };
  u16* w1h  = (u16*)alloc(256ULL * 32 * 512 * 2);   // w_hh1 packed
  u16* weff = (u16*)alloc(256ULL * 32 * 512 * 2);   // W_ih1 @ dec_w packed
  u16* w1x  = (u16*)alloc(256ULL * 6 * 512 * 2);    // w_ih1 packed (K padded to 192)
  u16* w2   = (u16*)alloc(256ULL * 64 * 512 * 2);   // [w_ih2 | w_hh2] packed
  u16* w3   = (u16*)alloc(256ULL * 64 * 512 * 2);   // [w_ih3 | w_hh3] packed
  u16* wdec = (u16*)alloc(171ULL * 1024 * 2);       // dec_w fp16 row-major
  u16* fr   = (u16*)alloc(100ULL * 64 * 192 * 2);   // frames fp16 padded
  u16* h0   = (u16*)alloc(101ULL * HSZ * 2);        // rotating h buffers
  u16* h1   = (u16*)alloc(101ULL * HSZ * 2);
  u16* h2   = (u16*)alloc(101ULL * HSZ * 2);
  float* br  = (float*)alloc(4096 * 4);
  float* ba  = (float*)alloc(4096 * 4);
  float* b2s = (float*)alloc(4096 * 4);
  float* b3s = (float*)alloc(4096 * 4);
  u32* bar   = (u32*)alloc(4096);
  (void)ws_size; (void)in_sizes; (void)n_in; (void)out_size;  // needs ~91 MiB of ws

  pack_w_kernel<<<256 * 32, 64, 0, stream>>>(w_hh1, 1024, nullptr, 0, w1h, 32);
  pack_w_kernel<<<256 * 6, 64, 0, stream>>>(w_ih1, 171, nullptr, 0, w1x, 6);
  pack_w_kernel<<<256 * 64, 64, 0, stream>>>(w_ih2, 1024, w_hh2, 1024, w2, 64);
  pack_w_kernel<<<256 * 64, 64, 0, stream>>>(w_ih3, 1024, w_hh3, 1024, w3, 64);
  pack_weff_kernel<<<256 * 32, 64, 0, stream>>>(w_ih1, dec_w, weff);
  pack_wdec_kernel<<<(171 * 1024 + 255) / 256, 256, 0, stream>>>(dec_w, wdec);
  pack_frames_kernel<<<100 * 64 * 192 / 256, 256, 0, stream>>>(real_seq, fr);
  prep_bias_kernel<<<16, 256, 0, stream>>>(b_ih1, b_hh1, w_ih1, dec_b,
                                           b_ih2, b_hh2, b_ih3, b_hh3, br, ba, b2s, b3s);
  zero_kernel<<<128, 256, 0, stream>>>((u32*)h0, (u32*)h1, (u32*)h2, bar);

  P p{w1h, weff, w1x, w2, w3, wdec, fr, br, ba, b2s, b3s, dec_b,
      h0, h1, h2, (float*)d_out, bar};
  lstm_main<<<256, 256, 0, stream>>>(p);
}

// Round 2
// 5745.078 us; speedup vs baseline: 1.1122x; 1.1122x over previous
//
#include <hip/hip_runtime.h>
#include <hip/hip_fp16.h>

// Persistent-kernel autoregressive LSTM for MI355X (gfx950).  Round 2.
//
// Round-1 lesson: per-window weight re-fetch (7.2 MB/window L2 misses) was the
// bottleneck. Now the 4 waves of each WG split K (not batch); each wave holds
// its distinct B-fragments permanently in ~200 VGPRs, so weights generate NO
// per-window memory traffic. Waves produce K-partial 64x16 tiles, reduced via
// LDS, then nonlinearity + c-state (registers) + coalesced device-scope h-store
// in [ng][b][4u] layout (512 B contiguous per WG). Grid barrier uses per-XCD
// arrival counters + per-XCD replicated release flags.

typedef unsigned short u16;
typedef unsigned int u32;
typedef _Float16 f16;
typedef _Float16 h8 __attribute__((ext_vector_type(8)));
typedef _Float16 h4 __attribute__((ext_vector_type(4)));
typedef float f4 __attribute__((ext_vector_type(4)));

#define HSZ 65536  // halves per h slot: layout [256 ng][64 b][4 u]

static __device__ __forceinline__ f4 mfma16(h8 a, h8 b, f4 c) {
  return __builtin_amdgcn_mfma_f32_16x16x32_f16(a, b, c, 0, 0, 0);
}

// GEMM over an h-layout ([ng][b][4u]) activation matrix, weights from regs.
// Wave w handles kt = w + 4*j. A-frag: lane holds A[m=16t+c][k0..k0+8) built
// from two 8B chunks at ngk=kt*8+q*2 and ngk+1.
template<int NJ>
static __device__ __forceinline__ void gemm_h(f4* acc, const u16* __restrict__ h,
                                              const h8* wr, int w, int q, int c) {
  const u16* base0 = h + (size_t)((w * 8 + q * 2) * 256 + c * 4);
#pragma unroll
  for (int j = 0; j < NJ; ++j) {
    const u16* hp = base0 + (size_t)j * 8192;
    h8 b = wr[j];
#pragma unroll
    for (int t = 0; t < 4; ++t) {
      h8 a;
      *(h4*)&a = *(const h4*)(hp + t * 64);
      *((h4*)&a + 1) = *(const h4*)(hp + 256 + t * 64);
      acc[t] = mfma16(a, b, acc[t]);
    }
  }
}

// GEMM over the row-major frame input [64][192].
static __device__ __forceinline__ void gemm_fr(f4* acc, const u16* __restrict__ frt,
                                               const h8* wr, int w, int q, int c) {
#pragma unroll
  for (int j = 0; j < 2; ++j) {
    int kt = w + 4 * j;
    if (kt < 6) {  // wave-uniform
      h8 b = wr[j];
#pragma unroll
      for (int t = 0; t < 4; ++t) {
        h8 a = *(const h8*)(frt + (size_t)(t * 16 + c) * 192 + kt * 32 + q * 8);
        acc[t] = mfma16(a, b, acc[t]);
      }
    }
  }
}

struct P {
  const u16 *w1h, *weff, *w1x, *w2, *w3, *wdec, *fr;
  const float *br, *ba, *b2s, *b3s, *dec_b;
  u16 *h0, *h1, *h2;
  float* out;
  u32* bar;
};

__launch_bounds__(256, 1)
__global__ void lstm_main(P p) {
  const int ng = blockIdx.x;        // unit-group: owns hidden units [4ng, 4ng+4)
  const int tid = threadIdx.x;
  const int lane = tid & 63;
  const int w = tid >> 6;           // wave = K-quarter (kt = w mod 4)
  const int c = lane & 15;          // B-frag col: gate = c>>2, unit = c&3
  const int q = lane >> 4;

  __shared__ float part[4 * 4 * 16 * 17];  // [wave][btile][m16][c16 pad17]
  __shared__ float decp[4][64];

  // ---- load all weight B-fragments into registers (once) ----
  h8 r_w1h[8], r_weff[8], r_w1x[2], r_w2[16], r_w3[16];
  {
    const size_t l8 = (size_t)lane * 8;
#pragma unroll
    for (int j = 0; j < 8; ++j) {
      r_w1h[j] = *(const h8*)(p.w1h + ((size_t)(ng * 32 + w + 4 * j) * 64) * 8 + l8);
      r_weff[j] = *(const h8*)(p.weff + ((size_t)(ng * 32 + w + 4 * j) * 64) * 8 + l8);
    }
#pragma unroll
    for (int j = 0; j < 2; ++j) {
      int kt = w + 4 * j;
      if (kt < 6)
        r_w1x[j] = *(const h8*)(p.w1x + ((size_t)(ng * 6 + kt) * 64) * 8 + l8);
    }
#pragma unroll
    for (int j = 0; j < 16; ++j) {
      r_w2[j] = *(const h8*)(p.w2 + ((size_t)(ng * 64 + w + 4 * j) * 64) * 8 + l8);
      r_w3[j] = *(const h8*)(p.w3 + ((size_t)(ng * 64 + w + 4 * j) * 64) * 8 + l8);
    }
  }

  float cr0[2] = {0.f, 0.f}, cr1[2] = {0.f, 0.f}, cr2[2] = {0.f, 0.f};
  u32 bidx = 0;

  auto put_part = [&](const f4* acc) {
#pragma unroll
    for (int t = 0; t < 4; ++t)
#pragma unroll
      for (int r = 0; r < 4; ++r)
        part[((w * 4 + t) * 16 + q * 4 + r) * 17 + c] = acc[t][r];
  };

  // Reduce partials, gates->nonlin, c-state update (regs), coalesced h-store.
  // tid<128: thread owns (b=tid>>1, units u2..u2+1), one u32 store each.
  auto combine = [&](float* crL, const float* __restrict__ bsrc, u16* hw) {
    if (tid < 128) {
      int b = tid >> 1, u2 = (tid & 1) * 2;
      int tt = b >> 4, mm = b & 15;
      u32 pk = 0;
#pragma unroll
      for (int e = 0; e < 2; ++e) {
        int u = u2 + e;
        float s0 = bsrc[0 * 1024 + ng * 4 + u];
        float s1 = bsrc[1 * 1024 + ng * 4 + u];
        float s2 = bsrc[2 * 1024 + ng * 4 + u];
        float s3 = bsrc[3 * 1024 + ng * 4 + u];
#pragma unroll
        for (int wv = 0; wv < 4; ++wv) {
          const float* pp = &part[((wv * 4 + tt) * 16 + mm) * 17 + u];
          s0 += pp[0]; s1 += pp[4]; s2 += pp[8]; s3 += pp[12];
        }
        float iv = 1.f / (1.f + __expf(-s0));
        float fv = 1.f / (1.f + __expf(-s1));
        float gv = tanhf(s2);
        float ov = 1.f / (1.f + __expf(-s3));
        float cn = fv * crL[e] + iv * gv;
        crL[e] = cn;
        f16 hh = (f16)(ov * tanhf(cn));
        pk |= ((u32)*(u16*)&hh) << (16 * e);
      }
      __hip_atomic_store((u32*)hw + (size_t)ng * 128 + tid, pk, __ATOMIC_RELAXED,
                         __HIP_MEMORY_SCOPE_AGENT);
    }
  };

  auto gridbar = [&]() {
    __syncthreads();  // per-wave s_waitcnt vmcnt(0): all h-stores visible at L3
    if (tid == 0) {
      ++bidx;
      u32 a = __hip_atomic_fetch_add(p.bar + (ng & 7) * 16, 1u, __ATOMIC_RELAXED,
                                     __HIP_MEMORY_SCOPE_AGENT);
      if (a == bidx * 32 - 1) {
        u32 g = __hip_atomic_fetch_add(p.bar + 128, 1u, __ATOMIC_RELAXED,
                                       __HIP_MEMORY_SCOPE_AGENT);
        if (g == bidx * 8 - 1) {
#pragma unroll
          for (int x = 0; x < 8; ++x)  // replicated release flags, one line/XCD
            __hip_atomic_store(p.bar + 256 + x * 16, bidx, __ATOMIC_RELAXED,
                               __HIP_MEMORY_SCOPE_AGENT);
        }
      }
      while (__hip_atomic_load(p.bar + 256 + (ng & 7) * 16, __ATOMIC_RELAXED,
                               __HIP_MEMORY_SCOPE_AGENT) < bidx)
        __builtin_amdgcn_s_sleep(4);
    }
    __syncthreads();
  };

  auto dec_partial = [&](const u16* __restrict__ h2b) {
    if (ng < 171) {
      int b = tid & 63, qq = tid >> 6;
      const u16* hp = h2b + qq * 64 * 256 + b * 4;
      const u16* wp = p.wdec + (size_t)ng * 1024 + qq * 256;
      float s = 0.f;
#pragma unroll 8
      for (int i = 0; i < 64; ++i) {
        h4 hv = *(const h4*)(hp + i * 256);
        h4 wv4 = *(const h4*)(wp + i * 4);
#pragma unroll
        for (int jj = 0; jj < 4; ++jj) s += (float)hv[jj] * (float)wv4[jj];
      }
      decp[qq][b] = s;
    }
  };
  auto dec_reduce = [&](int tout) {
    if (ng < 171 && tid < 64) {
      float o = decp[0][tid] + decp[1][tid] + decp[2][tid] + decp[3][tid] + p.dec_b[ng];
      p.out[(size_t)tid * 17100 + (size_t)tout * 171 + ng] = o;
    }
  };

  for (int t = 0; t < 100; ++t) {
    const bool cond = (t % 10) < 5;
    const u16* h0r = p.h0 + (size_t)t * HSZ;  // slot 0 = zeros
    const u16* h1r = p.h1 + (size_t)t * HSZ;
    const u16* h2r = p.h2 + (size_t)t * HSZ;
    u16* h0w = p.h0 + (size_t)(t + 1) * HSZ;
    u16* h1w = p.h1 + (size_t)(t + 1) * HSZ;
    u16* h2w = p.h2 + (size_t)(t + 1) * HSZ;

    // ---- window A: layer 1 (+ decoder for t-1, off critical path) ----
    {
      f4 acc[4] = {{0,0,0,0},{0,0,0,0},{0,0,0,0},{0,0,0,0}};
      gemm_h<8>(acc, h0r, r_w1h, w, q, c);
      if (cond) gemm_fr(acc, p.fr + (size_t)t * 64 * 192, r_w1x, w, q, c);
      else      gemm_h<8>(acc, h2r, r_weff, w, q, c);  // folded decoder feedback
      put_part(acc);
      if (t > 0) dec_partial(h2r);
      __syncthreads();
      combine(cr0, cond ? p.br : p.ba, h0w);
      if (t > 0) dec_reduce(t - 1);
      gridbar();
    }
    // ---- window B: layer 2 ----
    {
      f4 acc[4] = {{0,0,0,0},{0,0,0,0},{0,0,0,0},{0,0,0,0}};
      gemm_h<8>(acc, h0w, r_w2, w, q, c);
      gemm_h<8>(acc, h1r, r_w2 + 8, w, q, c);
      put_part(acc);
      __syncthreads();
      combine(cr1, p.b2s, h1w);
      gridbar();
    }
    // ---- window C: layer 3 ----
    {
      f4 acc[4] = {{0,0,0,0},{0,0,0,0},{0,0,0,0},{0,0,0,0}};
      gemm_h<8>(acc, h1w, r_w3, w, q, c);
      gemm_h<8>(acc, h2r, r_w3 + 8, w, q, c);
      put_part(acc);
      __syncthreads();
      combine(cr2, p.b3s, h2w);
      gridbar();
    }
  }
  // final decoder: out(99) from h2 slot 100 (visible after last barrier)
  dec_partial(p.h2 + (size_t)100 * HSZ);
  __syncthreads();
  dec_reduce(99);
}

// ------------------------- prep kernels -------------------------

// Pack [4096 x (KA+KB)] fp32 weights (two halves) into MFMA-B fragments:
// dst[((ng*nkt + kt)*64 + lane)*8 + j] = W[row(c)][kt*32 + (lane>>4)*8 + j]
// row(c) = (c>>2)*1024 + ng*4 + (c&3).  Zero-pads k >= KA+KB.
__global__ void pack_w_kernel(const float* __restrict__ srcA, int KA,
                              const float* __restrict__ srcB, int KB,
                              u16* __restrict__ dst, int nkt) {
  int blk = blockIdx.x;
  int ng = blk / nkt, kt = blk % nkt;
  int lane = threadIdx.x;
  int c = lane & 15, q = lane >> 4;
  int row = (c >> 2) * 1024 + ng * 4 + (c & 3);
  int k0 = kt * 32 + q * 8;
  alignas(16) u16 outv[8];
  for (int j = 0; j < 8; ++j) {
    int k = k0 + j;
    float v = 0.f;
    if (k < KA) v = srcA[(size_t)row * KA + k];
    else if (k - KA < KB) v = srcB[(size_t)row * KB + (k - KA)];
    f16 hv = (f16)v;
    outv[j] = *(u16*)&hv;
  }
  *(uint4*)(dst + ((size_t)blk * 64 + lane) * 8) = *(const uint4*)outv;
}

// W_eff[n][k] = sum_{r<171} w_ih1[n][r] * dec_w[r][k], MFMA-B packed fp16.
__global__ void pack_weff_kernel(const float* __restrict__ w_ih1,
                                 const float* __restrict__ dec_w, u16* __restrict__ dst) {
  int blk = blockIdx.x;  // ng*32 + kt
  int ng = blk >> 5, kt = blk & 31;
  int lane = threadIdx.x;
  int c = lane & 15, q = lane >> 4;
  int row = (c >> 2) * 1024 + ng * 4 + (c & 3);
  int k0 = kt * 32 + q * 8;
  float acc[8] = {0.f, 0.f, 0.f, 0.f, 0.f, 0.f, 0.f, 0.f};
  for (int r = 0; r < 171; ++r) {
    float wi = w_ih1[(size_t)row * 171 + r];
    const float* dw = dec_w + (size_t)r * 1024 + k0;
#pragma unroll
    for (int j = 0; j < 8; ++j) acc[j] += wi * dw[j];
  }
  alignas(16) u16 outv[8];
  for (int j = 0; j < 8; ++j) { f16 hv = (f16)acc[j]; outv[j] = *(u16*)&hv; }
  *(uint4*)(dst + ((size_t)blk * 64 + lane) * 8) = *(const uint4*)outv;
}

__global__ void prep_bias_kernel(const float* b_ih1, const float* b_hh1,
                                 const float* w_ih1, const float* dec_b,
                                 const float* b_ih2, const float* b_hh2,
                                 const float* b_ih3, const float* b_hh3,
                                 float* br, float* ba, float* b2, float* b3) {
  int n = blockIdx.x * 256 + threadIdx.x;  // 0..4095
  float s = b_ih1[n] + b_hh1[n];
  br[n] = s;
  float a = 0.f;
  for (int r = 0; r < 171; ++r) a += w_ih1[(size_t)n * 171 + r] * dec_b[r];
  ba[n] = s + a;  // autoregressive path: + W_ih1 @ dec_b
  b2[n] = b_ih2[n] + b_hh2[n];
  b3[n] = b_ih3[n] + b_hh3[n];
}

// real_seq [64][100][171] fp32 -> fr16 [100][64][192] fp16 (zero-padded K)
__global__ void pack_frames_kernel(const float* __restrict__ rs, u16* __restrict__ fr) {
  int i = blockIdx.x * 256 + threadIdx.x;
  int j = i % 192;
  int tb = i / 192;
  int b = tb % 64, t = tb / 64;
  float v = (j < 171) ? rs[((size_t)b * 100 + t) * 171 + j] : 0.f;
  f16 hv = (f16)v;
  fr[i] = *(u16*)&hv;
}

__global__ void pack_wdec_kernel(const float* __restrict__ dw, u16* __restrict__ dst) {
  int i = blockIdx.x * 256 + threadIdx.x;
  if (i < 171 * 1024) { f16 hv = (f16)dw[i]; dst[i] = *(u16*)&hv; }
}

// zero h slot 0 of each buffer (initial state) and the barrier page
__global__ void zero_kernel(u32* h0, u32* h1, u32* h2, u32* bar) {
  int i = blockIdx.x * 256 + threadIdx.x;  // 0..32767
  h0[i] = 0; h1[i] = 0; h2[i] = 0;
  if (blockIdx.x == 0) {
    bar[threadIdx.x] = 0; bar[256 + threadIdx.x] = 0;
    bar[512 + threadIdx.x] = 0; bar[768 + threadIdx.x] = 0;
  }
}

extern "C" void kernel_launch(void* const* d_in, const int* in_sizes, int n_in,
                              void* d_out, int out_size, void* d_ws, size_t ws_size,
                              hipStream_t stream) {
  const float* real_seq = (const float*)d_in[0];
  const float* w_ih1 = (const float*)d_in[1];
  const float* w_hh1 = (const float*)d_in[2];
  const float* b_ih1 = (const float*)d_in[3];
  const float* b_hh1 = (const float*)d_in[4];
  const float* w_ih2 = (const float*)d_in[5];
  const float* w_hh2 = (const float*)d_in[6];
  const float* b_ih2 = (const float*)d_in[7];
  const float* b_hh2 = (const float*)d_in[8];
  const float* w_ih3 = (const float*)d_in[9];
  const float* w_hh3 = (const float*)d_in[10];
  const float* b_ih3 = (const float*)d_in[11];
  const float* b_hh3 = (const float*)d_in[12];
  const float* dec_w = (const float*)d_in[13];
  const float* dec_b = (const float*)d_in[14];

  char* ws = (char*)d_ws;
  size_t off = 0;
  auto alloc = [&](size_t bytes) {
    char* pp = ws + off;
    off += (bytes + 255) & ~(size_t)255;
    return pp;
  };
  u16* w1h  = (u16*)alloc(256ULL * 32 * 512 * 2);   // w_hh1 packed
  u16* weff = (u16*)alloc(256ULL * 32 * 512 * 2);   // W_ih1 @ dec_w packed
  u16* w1x  = (u16*)alloc(256ULL * 6 * 512 * 2);    // w_ih1 packed (K padded 192)
  u16* w2   = (u16*)alloc(256ULL * 64 * 512 * 2);   // [w_ih2 | w_hh2] packed
  u16* w3   = (u16*)alloc(256ULL * 64 * 512 * 2);   // [w_ih3 | w_hh3] packed
  u16* wdec = (u16*)alloc(171ULL * 1024 * 2);       // dec_w fp16 row-major
  u16* fr   = (u16*)alloc(100ULL * 64 * 192 * 2);   // frames fp16 padded
  u16* h0   = (u16*)alloc(101ULL * HSZ * 2);        // rotating h, [ng][b][4u]
  u16* h1   = (u16*)alloc(101ULL * HSZ * 2);
  u16* h2   = (u16*)alloc(101ULL * HSZ * 2);
  float* br  = (float*)alloc(4096 * 4);
  float* ba  = (float*)alloc(4096 * 4);
  float* b2s = (float*)alloc(4096 * 4);
  float* b3s = (float*)alloc(4096 * 4);
  u32* bar   = (u32*)alloc(4096);
  (void)ws_size; (void)in_sizes; (void)n_in; (void)out_size;  // needs ~91 MiB ws

  pack_w_kernel<<<256 * 32, 64, 0, stream>>>(w_hh1, 1024, nullptr, 0, w1h, 32);
  pack_w_kernel<<<256 * 6, 64, 0, stream>>>(w_ih1, 171, nullptr, 0, w1x, 6);
  pack_w_kernel<<<256 * 64, 64, 0, stream>>>(w_ih2, 1024, w_hh2, 1024, w2, 64);
  pack_w_kernel<<<256 * 64, 64, 0, stream>>>(w_ih3, 1024, w_hh3, 1024, w3, 64);
  pack_weff_kernel<<<256 * 32, 64, 0, stream>>>(w_ih1, dec_w, weff);
  pack_wdec_kernel<<<(171 * 1024 + 255) / 256, 256, 0, stream>>>(dec_w, wdec);
  pack_frames_kernel<<<100 * 64 * 192 / 256, 256, 0, stream>>>(real_seq, fr);
  prep_bias_kernel<<<16, 256, 0, stream>>>(b_ih1, b_hh1, w_ih1, dec_b,
                                           b_ih2, b_hh2, b_ih3, b_hh3, br, ba, b2s, b3s);
  zero_kernel<<<128, 256, 0, stream>>>((u32*)h0, (u32*)h1, (u32*)h2, bar);

  P p{w1h, weff, w1x, w2, w3, wdec, fr, br, ba, b2s, b3s, dec_b,
      h0, h1, h2, (float*)d_out, bar};
  lstm_main<<<256, 256, 0, stream>>>(p);
}

// Round 3
// 2171.717 us; speedup vs baseline: 2.9421x; 2.6454x over previous
//
#include <hip/hip_runtime.h>
#include <hip/hip_fp16.h>

// Persistent-kernel autoregressive LSTM for MI355X (gfx950).  Round 3.
//
// R2 post-mortem: VGPR=176 (<200 needed) + WRITE_SIZE excess proved weights
// spilled to scratch and were reloaded every window; occupancy 12.4% = 1
// wave/SIMD left all load latency exposed. R3: 8 waves/WG (2/SIMD), w2/w3 in
// LDS (128 KB, loaded once), w1h/weff/w1x in ~72 VGPRs/wave (K-quarter x
// batch-half split), h layout [k/8][b][8] so A-frags are single 16B loads.

typedef unsigned short u16;
typedef unsigned int u32;
typedef _Float16 f16;
typedef _Float16 h8 __attribute__((ext_vector_type(8)));
typedef float f4 __attribute__((ext_vector_type(4)));

#define HSZ 65536  // halves per h slot: layout [128 kgrp][64 b][8 u]

static __device__ __forceinline__ f4 mfma16(h8 a, h8 b, f4 c) {
  return __builtin_amdgcn_mfma_f32_16x16x32_f16(a, b, c, 0, 0, 0);
}

struct P {
  const u16 *w1h, *weff, *w1x, *w2, *w3, *wdec, *fr;
  const float *br, *ba, *b2s, *b3s, *dec_b;
  u16 *h0, *h1, *h2;
  float* out;
  u32* bar;
};

// A-frag (16x32 tile): lane(q=lane>>4, c=lane&15) holds A[m=c][k=q*8+j].
// h element [b][k] lives at [(k>>3)*512 + b*8 + (k&7)] -> one h8 load.
// Wave (kq, bt2) covers K-quarter kq (8 kt) x batch rows [bt2*32, bt2*32+32).
template<int NJ>
static __device__ __forceinline__ void gemm_hreg(f4* acc, const u16* __restrict__ h,
                                                 const h8 (&wr)[NJ], int kq, int bt2,
                                                 int q, int c) {
#pragma unroll
  for (int jj = 0; jj < NJ; ++jj) {
    int kt = kq * 8 + jj;
    const u16* hp = h + (size_t)(kt * 4 + q) * 512;
    h8 b = wr[jj];
#pragma unroll
    for (int t = 0; t < 2; ++t) {
      h8 a = *(const h8*)(hp + ((bt2 * 2 + t) * 16 + c) * 8);
      acc[t] = mfma16(a, b, acc[t]);
    }
  }
}

// Same, weights from LDS (w2/w3), kt offset by ktbase.
static __device__ __forceinline__ void gemm_hlds(f4* acc, const u16* __restrict__ h,
                                                 const u16* lw, int ktbase, int kq,
                                                 int bt2, int q, int c, int lane) {
#pragma unroll
  for (int jj = 0; jj < 8; ++jj) {
    int kt = kq * 8 + jj;
    h8 b = *(const h8*)(lw + (size_t)((ktbase + kt) * 64 + lane) * 8);
    const u16* hp = h + (size_t)(kt * 4 + q) * 512;
#pragma unroll
    for (int t = 0; t < 2; ++t) {
      h8 a = *(const h8*)(hp + ((bt2 * 2 + t) * 16 + c) * 8);
      acc[t] = mfma16(a, b, acc[t]);
    }
  }
}

// Frame input [64][192] row-major; kt in [0,6) mapped kt = kq*2+jj, kq<3.
static __device__ __forceinline__ void gemm_fr(f4* acc, const u16* __restrict__ frt,
                                               const h8 (&wr)[2], int kq, int bt2,
                                               int q, int c) {
  if (kq < 3) {
#pragma unroll
    for (int jj = 0; jj < 2; ++jj) {
      int kt = kq * 2 + jj;
      h8 b = wr[jj];
#pragma unroll
      for (int t = 0; t < 2; ++t) {
        h8 a = *(const h8*)(frt + (size_t)((bt2 * 2 + t) * 16 + c) * 192 + kt * 32 + q * 8);
        acc[t] = mfma16(a, b, acc[t]);
      }
    }
  }
}

__launch_bounds__(512, 2)
__global__ void lstm_main(P p) {
  const int ng = blockIdx.x;        // unit-group: owns hidden units [4ng, 4ng+4)
  const int tid = threadIdx.x;
  const int lane = tid & 63;
  const int w = tid >> 6;           // 8 waves
  const int kq = w & 3;             // K-quarter
  const int bt2 = w >> 2;           // batch half
  const int c = lane & 15;
  const int q = lane >> 4;

  __shared__ u16 lds_w2[64 * 512];       // 64 KB  [kt][lane][8] B-frags
  __shared__ u16 lds_w3[64 * 512];       // 64 KB
  __shared__ float part[4 * 64 * 17];    // [kq][brow][c pad17]
  __shared__ float decp[8][64];

  // ---- one-time: stage w2/w3 slices into LDS ----
  {
    const uint4* s2 = (const uint4*)(p.w2 + (size_t)ng * 64 * 512);
    const uint4* s3 = (const uint4*)(p.w3 + (size_t)ng * 64 * 512);
    uint4* d2 = (uint4*)lds_w2;
    uint4* d3 = (uint4*)lds_w3;
    for (int i = tid; i < 4096; i += 512) { d2[i] = s2[i]; d3[i] = s3[i]; }
  }

  // ---- one-time: w1h/weff/w1x B-frags into registers (~72 VGPR/wave) ----
  h8 r_w1h[8], r_weff[8], r_w1x[2];
  {
#pragma unroll
    for (int jj = 0; jj < 8; ++jj) {
      r_w1h[jj] = *(const h8*)(p.w1h + (size_t)((ng * 32 + kq * 8 + jj) * 64 + lane) * 8);
      r_weff[jj] = *(const h8*)(p.weff + (size_t)((ng * 32 + kq * 8 + jj) * 64 + lane) * 8);
    }
    if (kq < 3) {
#pragma unroll
      for (int jj = 0; jj < 2; ++jj)
        r_w1x[jj] = *(const h8*)(p.w1x + (size_t)((ng * 6 + kq * 2 + jj) * 64 + lane) * 8);
    }
  }
  __syncthreads();

  float cr0[2] = {0.f, 0.f}, cr1[2] = {0.f, 0.f}, cr2[2] = {0.f, 0.f};
  u32 bidx = 0;

  auto put_part = [&](const f4* acc) {
#pragma unroll
    for (int t = 0; t < 2; ++t)
#pragma unroll
      for (int r = 0; r < 4; ++r)
        part[(kq * 64 + bt2 * 32 + t * 16 + q * 4 + r) * 17 + c] = acc[t][r];
  };

  // Reduce 4 K-partials, nonlin, c-state (regs), coalesced agent-scope h-store.
  auto combine = [&](float* crL, const float* __restrict__ bsrc, u16* hw) {
    if (tid < 128) {
      int b = tid >> 1, u2 = (tid & 1) * 2;
      u32 pk = 0;
#pragma unroll
      for (int e = 0; e < 2; ++e) {
        int u = u2 + e;
        float s[4];
#pragma unroll
        for (int g = 0; g < 4; ++g) {
          float sv = bsrc[g * 1024 + ng * 4 + u];
#pragma unroll
          for (int kqi = 0; kqi < 4; ++kqi)
            sv += part[(kqi * 64 + b) * 17 + g * 4 + u];
          s[g] = sv;
        }
        float iv = 1.f / (1.f + __expf(-s[0]));
        float fv = 1.f / (1.f + __expf(-s[1]));
        float gv = tanhf(s[2]);
        float ov = 1.f / (1.f + __expf(-s[3]));
        float cn = fv * crL[e] + iv * gv;
        crL[e] = cn;
        f16 hh = (f16)(ov * tanhf(cn));
        pk |= ((u32)*(u16*)&hh) << (16 * e);
      }
      // h[b][4ng+u] -> halves at (ng>>1)*512 + b*8 + (ng&1)*4 + u2
      u32* dst = (u32*)hw + (size_t)(ng >> 1) * 256 + b * 4 + (ng & 1) * 2 + (tid & 1);
      __hip_atomic_store(dst, pk, __ATOMIC_RELAXED, __HIP_MEMORY_SCOPE_AGENT);
    }
  };

  auto gridbar = [&]() {
    __syncthreads();  // drains vmcnt: h-stores visible at coherence point
    if (tid == 0) {
      ++bidx;
      u32 a = __hip_atomic_fetch_add(p.bar + (ng & 7) * 32, 1u, __ATOMIC_RELAXED,
                                     __HIP_MEMORY_SCOPE_AGENT);
      if (a == bidx * 32 - 1) {
        u32 g = __hip_atomic_fetch_add(p.bar + 512, 1u, __ATOMIC_RELAXED,
                                       __HIP_MEMORY_SCOPE_AGENT);
        if (g == bidx * 8 - 1) {
#pragma unroll
          for (int x = 0; x < 8; ++x)
            __hip_atomic_store(p.bar + 1024 + x * 32, bidx, __ATOMIC_RELAXED,
                               __HIP_MEMORY_SCOPE_AGENT);
        }
      }
      while (__hip_atomic_load(p.bar + 1024 + (ng & 7) * 32, __ATOMIC_RELAXED,
                               __HIP_MEMORY_SCOPE_AGENT) < bidx)
        __builtin_amdgcn_s_sleep(2);
    }
    __syncthreads();
  };

  auto dec_partial = [&](const u16* __restrict__ h2b) {
    if (ng < 171) {
      const u16* hp = h2b + (size_t)w * 16 * 512 + lane * 8;
      const u16* wp = p.wdec + (size_t)ng * 1024 + w * 128;
      float s = 0.f;
#pragma unroll 4
      for (int i = 0; i < 16; ++i) {
        h8 hv = *(const h8*)(hp + (size_t)i * 512);
        h8 wv8 = *(const h8*)(wp + i * 8);
#pragma unroll
        for (int jj = 0; jj < 8; ++jj) s += (float)hv[jj] * (float)wv8[jj];
      }
      decp[w][lane] = s;
    }
  };
  auto dec_reduce = [&](int tout) {
    if (ng < 171 && tid < 64) {
      float o = p.dec_b[ng];
#pragma unroll
      for (int i = 0; i < 8; ++i) o += decp[i][tid];
      p.out[(size_t)tid * 17100 + (size_t)tout * 171 + ng] = o;
    }
  };

  for (int t = 0; t < 100; ++t) {
    const bool cond = (t % 10) < 5;
    const u16* h0r = p.h0 + (size_t)t * HSZ;  // slot 0 = zeros
    const u16* h1r = p.h1 + (size_t)t * HSZ;
    const u16* h2r = p.h2 + (size_t)t * HSZ;
    u16* h0w = p.h0 + (size_t)(t + 1) * HSZ;
    u16* h1w = p.h1 + (size_t)(t + 1) * HSZ;
    u16* h2w = p.h2 + (size_t)(t + 1) * HSZ;

    // ---- window A: layer 1 (+ decoder for t-1, off critical path) ----
    {
      f4 acc[2] = {{0, 0, 0, 0}, {0, 0, 0, 0}};
      gemm_hreg<8>(acc, h0r, r_w1h, kq, bt2, q, c);
      if (cond) gemm_fr(acc, p.fr + (size_t)t * 64 * 192, r_w1x, kq, bt2, q, c);
      else      gemm_hreg<8>(acc, h2r, r_weff, kq, bt2, q, c);  // folded feedback
      put_part(acc);
      if (t > 0) dec_partial(h2r);
      __syncthreads();
      combine(cr0, cond ? p.br : p.ba, h0w);
      if (t > 0) dec_reduce(t - 1);
      gridbar();
    }
    // ---- window B: layer 2 ----
    {
      f4 acc[2] = {{0, 0, 0, 0}, {0, 0, 0, 0}};
      gemm_hlds(acc, h0w, lds_w2, 0, kq, bt2, q, c, lane);
      gemm_hlds(acc, h1r, lds_w2, 32, kq, bt2, q, c, lane);
      put_part(acc);
      __syncthreads();
      combine(cr1, p.b2s, h1w);
      gridbar();
    }
    // ---- window C: layer 3 ----
    {
      f4 acc[2] = {{0, 0, 0, 0}, {0, 0, 0, 0}};
      gemm_hlds(acc, h1w, lds_w3, 0, kq, bt2, q, c, lane);
      gemm_hlds(acc, h2r, lds_w3, 32, kq, bt2, q, c, lane);
      put_part(acc);
      __syncthreads();
      combine(cr2, p.b3s, h2w);
      gridbar();
    }
  }
  // final decoder: out(99) from h2 slot 100 (visible after last barrier)
  dec_partial(p.h2 + (size_t)100 * HSZ);
  __syncthreads();
  dec_reduce(99);
}

// ------------------------- prep kernels -------------------------

// Pack [4096 x (KA+KB)] fp32 weights (two halves) into MFMA-B fragments:
// dst[((ng*nkt + kt)*64 + lane)*8 + j] = W[row(c)][kt*32 + (lane>>4)*8 + j]
// row(c) = (c>>2)*1024 + ng*4 + (c&3).  Zero-pads k >= KA+KB.
__global__ void pack_w_kernel(const float* __restrict__ srcA, int KA,
                              const float* __restrict__ srcB, int KB,
                              u16* __restrict__ dst, int nkt) {
  int blk = blockIdx.x;
  int ng = blk / nkt, kt = blk % nkt;
  int lane = threadIdx.x;
  int c = lane & 15, q = lane >> 4;
  int row = (c >> 2) * 1024 + ng * 4 + (c & 3);
  int k0 = kt * 32 + q * 8;
  alignas(16) u16 outv[8];
  for (int j = 0; j < 8; ++j) {
    int k = k0 + j;
    float v = 0.f;
    if (k < KA) v = srcA[(size_t)row * KA + k];
    else if (k - KA < KB) v = srcB[(size_t)row * KB + (k - KA)];
    f16 hv = (f16)v;
    outv[j] = *(u16*)&hv;
  }
  *(uint4*)(dst + ((size_t)blk * 64 + lane) * 8) = *(const uint4*)outv;
}

// W_eff[n][k] = sum_{r<171} w_ih1[n][r] * dec_w[r][k], MFMA-B packed fp16.
__global__ void pack_weff_kernel(const float* __restrict__ w_ih1,
                                 const float* __restrict__ dec_w, u16* __restrict__ dst) {
  int blk = blockIdx.x;  // ng*32 + kt
  int ng = blk >> 5, kt = blk & 31;
  int lane = threadIdx.x;
  int c = lane & 15, q = lane >> 4;
  int row = (c >> 2) * 1024 + ng * 4 + (c & 3);
  int k0 = kt * 32 + q * 8;
  float acc[8] = {0.f, 0.f, 0.f, 0.f, 0.f, 0.f, 0.f, 0.f};
  for (int r = 0; r < 171; ++r) {
    float wi = w_ih1[(size_t)row * 171 + r];
    const float* dw = dec_w + (size_t)r * 1024 + k0;
#pragma unroll
    for (int j = 0; j < 8; ++j) acc[j] += wi * dw[j];
  }
  alignas(16) u16 outv[8];
  for (int j = 0; j < 8; ++j) { f16 hv = (f16)acc[j]; outv[j] = *(u16*)&hv; }
  *(uint4*)(dst + ((size_t)blk * 64 + lane) * 8) = *(const uint4*)outv;
}

__global__ void prep_bias_kernel(const float* b_ih1, const float* b_hh1,
                                 const float* w_ih1, const float* dec_b,
                                 const float* b_ih2, const float* b_hh2,
                                 const float* b_ih3, const float* b_hh3,
                                 float* br, float* ba, float* b2, float* b3) {
  int n = blockIdx.x * 256 + threadIdx.x;  // 0..4095
  float s = b_ih1[n] + b_hh1[n];
  br[n] = s;
  float a = 0.f;
  for (int r = 0; r < 171; ++r) a += w_ih1[(size_t)n * 171 + r] * dec_b[r];
  ba[n] = s + a;  // autoregressive path: + W_ih1 @ dec_b
  b2[n] = b_ih2[n] + b_hh2[n];
  b3[n] = b_ih3[n] + b_hh3[n];
}

// real_seq [64][100][171] fp32 -> fr16 [100][64][192] fp16 (zero-padded K)
__global__ void pack_frames_kernel(const float* __restrict__ rs, u16* __restrict__ fr) {
  int i = blockIdx.x * 256 + threadIdx.x;
  int j = i % 192;
  int tb = i / 192;
  int b = tb % 64, t = tb / 64;
  float v = (j < 171) ? rs[((size_t)b * 100 + t) * 171 + j] : 0.f;
  f16 hv = (f16)v;
  fr[i] = *(u16*)&hv;
}

__global__ void pack_wdec_kernel(const float* __restrict__ dw, u16* __restrict__ dst) {
  int i = blockIdx.x * 256 + threadIdx.x;
  if (i < 171 * 1024) { f16 hv = (f16)dw[i]; dst[i] = *(u16*)&hv; }
}

// zero h slot 0 of each buffer (initial state) and the barrier page (8 KB)
__global__ void zero_kernel(u32* h0, u32* h1, u32* h2, u32* bar) {
  int i = blockIdx.x * 256 + threadIdx.x;  // 0..32767
  h0[i] = 0; h1[i] = 0; h2[i] = 0;
  if (blockIdx.x < 8) bar[i] = 0;  // 2048 u32
}

extern "C" void kernel_launch(void* const* d_in, const int* in_sizes, int n_in,
                              void* d_out, int out_size, void* d_ws, size_t ws_size,
                              hipStream_t stream) {
  const float* real_seq = (const float*)d_in[0];
  const float* w_ih1 = (const float*)d_in[1];
  const float* w_hh1 = (const float*)d_in[2];
  const float* b_ih1 = (const float*)d_in[3];
  const float* b_hh1 = (const float*)d_in[4];
  const float* w_ih2 = (const float*)d_in[5];
  const float* w_hh2 = (const float*)d_in[6];
  const float* b_ih2 = (const float*)d_in[7];
  const float* b_hh2 = (const float*)d_in[8];
  const float* w_ih3 = (const float*)d_in[9];
  const float* w_hh3 = (const float*)d_in[10];
  const float* b_ih3 = (const float*)d_in[11];
  const float* b_hh3 = (const float*)d_in[12];
  const float* dec_w = (const float*)d_in[13];
  const float* dec_b = (const float*)d_in[14];

  char* ws = (char*)d_ws;
  size_t off = 0;
  auto alloc = [&](size_t bytes) {
    char* pp = ws + off;
    off += (bytes + 255) & ~(size_t)255;
    return pp;
  };
  u16* w1h  = (u16*)alloc(256ULL * 32 * 512 * 2);   // w_hh1 packed
  u16* weff = (u16*)alloc(256ULL * 32 * 512 * 2);   // W_ih1 @ dec_w packed
  u16* w1x  = (u16*)alloc(256ULL * 6 * 512 * 2);    // w_ih1 packed (K padded 192)
  u16* w2   = (u16*)alloc(256ULL * 64 * 512 * 2);   // [w_ih2 | w_hh2] packed
  u16* w3   = (u16*)alloc(256ULL * 64 * 512 * 2);   // [w_ih3 | w_hh3] packed
  u16* wdec = (u16*)alloc(171ULL * 1024 * 2);       // dec_w fp16 row-major
  u16* fr   = (u16*)alloc(100ULL * 64 * 192 * 2);   // frames fp16 padded
  u16* h0   = (u16*)alloc(101ULL * HSZ * 2);        // rotating h, [k/8][b][8]
  u16* h1   = (u16*)alloc(101ULL * HSZ * 2);
  u16* h2   = (u16*)alloc(101ULL * HSZ * 2);
  float* br  = (float*)alloc(4096 * 4);
  float* ba  = (float*)alloc(4096 * 4);
  float* b2s = (float*)alloc(4096 * 4);
  float* b3s = (float*)alloc(4096 * 4);
  u32* bar   = (u32*)alloc(8192);
  (void)ws_size; (void)in_sizes; (void)n_in; (void)out_size;  // needs ~91 MiB ws

  pack_w_kernel<<<256 * 32, 64, 0, stream>>>(w_hh1, 1024, nullptr, 0, w1h, 32);
  pack_w_kernel<<<256 * 6, 64, 0, stream>>>(w_ih1, 171, nullptr, 0, w1x, 6);
  pack_w_kernel<<<256 * 64, 64, 0, stream>>>(w_ih2, 1024, w_hh2, 1024, w2, 64);
  pack_w_kernel<<<256 * 64, 64, 0, stream>>>(w_ih3, 1024, w_hh3, 1024, w3, 64);
  pack_weff_kernel<<<256 * 32, 64, 0, stream>>>(w_ih1, dec_w, weff);
  pack_wdec_kernel<<<(171 * 1024 + 255) / 256, 256, 0, stream>>>(dec_w, wdec);
  pack_frames_kernel<<<100 * 64 * 192 / 256, 256, 0, stream>>>(real_seq, fr);
  prep_bias_kernel<<<16, 256, 0, stream>>>(b_ih1, b_hh1, w_ih1, dec_b,
                                           b_ih2, b_hh2, b_ih3, b_hh3, br, ba, b2s, b3s);
  zero_kernel<<<128, 256, 0, stream>>>((u32*)h0, (u32*)h1, (u32*)h2, bar);

  P p{w1h, weff, w1x, w2, w3, wdec, fr, br, ba, b2s, b3s, dec_b,
      h0, h1, h2, (float*)d_out, bar};
  lstm_main<<<256, 512, 0, stream>>>(p);
}

// Round 4
// 2130.949 us; speedup vs baseline: 2.9984x; 1.0191x over previous
//
#include <hip/hip_runtime.h>
#include <hip/hip_fp16.h>

// Persistent-kernel autoregressive LSTM for MI355X (gfx950).  Round 4.
//
// R3 post-mortem: window = 6.4 us, ~95% sync latency (atomic-tree barrier +
// poll round trips, all serial with compute). R4: (1) flat slot barrier --
// each WG stores its own slot, every WG's wave-0 polls all 256 slots directly
// (no atomics, 1 L3 round trip instead of 3); (2) arrive/wait split: the
// stale-K-half gemm (operand published 3 windows ago) executes BETWEEN arrive
// and wait, overlapping barrier propagation; only the fresh-half gemm (operand
// from the previous window) runs post-barrier.

typedef unsigned short u16;
typedef unsigned int u32;
typedef _Float16 f16;
typedef _Float16 h8 __attribute__((ext_vector_type(8)));
typedef float f4 __attribute__((ext_vector_type(4)));

#define HSZ 65536  // halves per h slot: layout [128 kgrp][64 b][8 u]

static __device__ __forceinline__ f4 mfma16(h8 a, h8 b, f4 c) {
  return __builtin_amdgcn_mfma_f32_16x16x32_f16(a, b, c, 0, 0, 0);
}

struct P {
  const u16 *w1h, *weff, *w1x, *w2, *w3, *wdec, *fr;
  const float *br, *ba, *b2s, *b3s, *dec_b;
  u16 *h0, *h1, *h2;
  float* out;
  u32* bar;
};

// A-frag (16x32 tile): lane(q=lane>>4, c=lane&15) holds A[m=c][k=q*8+j].
// h element [b][k] lives at [(k>>3)*512 + b*8 + (k&7)] -> one h8 load.
// Wave (kq, bt2) covers K-quarter kq (8 kt) x batch rows [bt2*32, bt2*32+32).
template<int NJ>
static __device__ __forceinline__ void gemm_hreg(f4* acc, const u16* __restrict__ h,
                                                 const h8 (&wr)[NJ], int kq, int bt2,
                                                 int q, int c) {
#pragma unroll
  for (int jj = 0; jj < NJ; ++jj) {
    int kt = kq * 8 + jj;
    const u16* hp = h + (size_t)(kt * 4 + q) * 512;
    h8 b = wr[jj];
#pragma unroll
    for (int t = 0; t < 2; ++t) {
      h8 a = *(const h8*)(hp + ((bt2 * 2 + t) * 16 + c) * 8);
      acc[t] = mfma16(a, b, acc[t]);
    }
  }
}

// Same, weights from LDS (w2/w3), kt offset by ktbase.
static __device__ __forceinline__ void gemm_hlds(f4* acc, const u16* __restrict__ h,
                                                 const u16* lw, int ktbase, int kq,
                                                 int bt2, int q, int c, int lane) {
#pragma unroll
  for (int jj = 0; jj < 8; ++jj) {
    int kt = kq * 8 + jj;
    h8 b = *(const h8*)(lw + (size_t)((ktbase + kt) * 64 + lane) * 8);
    const u16* hp = h + (size_t)(kt * 4 + q) * 512;
#pragma unroll
    for (int t = 0; t < 2; ++t) {
      h8 a = *(const h8*)(hp + ((bt2 * 2 + t) * 16 + c) * 8);
      acc[t] = mfma16(a, b, acc[t]);
    }
  }
}

// Frame input [64][192] row-major; kt in [0,6) mapped kt = kq*2+jj, kq<3.
static __device__ __forceinline__ void gemm_fr(f4* acc, const u16* __restrict__ frt,
                                               const h8 (&wr)[2], int kq, int bt2,
                                               int q, int c) {
  if (kq < 3) {
#pragma unroll
    for (int jj = 0; jj < 2; ++jj) {
      int kt = kq * 2 + jj;
      h8 b = wr[jj];
#pragma unroll
      for (int t = 0; t < 2; ++t) {
        h8 a = *(const h8*)(frt + (size_t)((bt2 * 2 + t) * 16 + c) * 192 + kt * 32 + q * 8);
        acc[t] = mfma16(a, b, acc[t]);
      }
    }
  }
}

__launch_bounds__(512, 2)
__global__ void lstm_main(P p) {
  const int ng = blockIdx.x;        // unit-group: owns hidden units [4ng, 4ng+4)
  const int tid = threadIdx.x;
  const int lane = tid & 63;
  const int w = tid >> 6;           // 8 waves
  const int kq = w & 3;             // K-quarter
  const int bt2 = w >> 2;           // batch half
  const int c = lane & 15;
  const int q = lane >> 4;

  __shared__ u16 lds_w2[64 * 512];       // 64 KB  [kt][lane][8] B-frags
  __shared__ u16 lds_w3[64 * 512];       // 64 KB
  __shared__ float part[4 * 64 * 17];    // [kq][brow][c pad17]
  __shared__ float decp[8][64];

  // ---- one-time: stage w2/w3 slices into LDS ----
  {
    const uint4* s2 = (const uint4*)(p.w2 + (size_t)ng * 64 * 512);
    const uint4* s3 = (const uint4*)(p.w3 + (size_t)ng * 64 * 512);
    uint4* d2 = (uint4*)lds_w2;
    uint4* d3 = (uint4*)lds_w3;
    for (int i = tid; i < 4096; i += 512) { d2[i] = s2[i]; d3[i] = s3[i]; }
  }

  // ---- one-time: w1h/weff/w1x B-frags into registers (~72 VGPR/wave) ----
  h8 r_w1h[8], r_weff[8], r_w1x[2];
  {
#pragma unroll
    for (int jj = 0; jj < 8; ++jj) {
      r_w1h[jj] = *(const h8*)(p.w1h + (size_t)((ng * 32 + kq * 8 + jj) * 64 + lane) * 8);
      r_weff[jj] = *(const h8*)(p.weff + (size_t)((ng * 32 + kq * 8 + jj) * 64 + lane) * 8);
    }
    if (kq < 3) {
#pragma unroll
      for (int jj = 0; jj < 2; ++jj)
        r_w1x[jj] = *(const h8*)(p.w1x + (size_t)((ng * 6 + kq * 2 + jj) * 64 + lane) * 8);
    }
  }
  __syncthreads();

  float cr0[2] = {0.f, 0.f}, cr1[2] = {0.f, 0.f}, cr2[2] = {0.f, 0.f};
  u32 bidx = 0;

  // Publish: drain all waves' h-stores (vmcnt0 at s_barrier), then mark slot.
  auto arrive = [&]() {
    __syncthreads();
    ++bidx;
    if (tid == 0)
      __hip_atomic_store(p.bar + ng, bidx, __ATOMIC_RELAXED, __HIP_MEMORY_SCOPE_AGENT);
  };
  // Wave 0 polls all 256 slots (4 coalesced agent loads + ballot); others park
  // at s_barrier. No atomics, no central aggregator, 1 L3 RT per check.
  auto waitall = [&]() {
    if (w == 0) {
      for (;;) {
        u32 v0 = __hip_atomic_load(p.bar + lane, __ATOMIC_RELAXED, __HIP_MEMORY_SCOPE_AGENT);
        u32 v1 = __hip_atomic_load(p.bar + 64 + lane, __ATOMIC_RELAXED, __HIP_MEMORY_SCOPE_AGENT);
        u32 v2 = __hip_atomic_load(p.bar + 128 + lane, __ATOMIC_RELAXED, __HIP_MEMORY_SCOPE_AGENT);
        u32 v3 = __hip_atomic_load(p.bar + 192 + lane, __ATOMIC_RELAXED, __HIP_MEMORY_SCOPE_AGENT);
        u32 m01 = v0 < v1 ? v0 : v1;
        u32 m23 = v2 < v3 ? v2 : v3;
        u32 mn = m01 < m23 ? m01 : m23;
        if (__all((int)(mn >= bidx))) break;
      }
    }
    __syncthreads();
  };

  auto put_part = [&](const f4* acc) {
#pragma unroll
    for (int t = 0; t < 2; ++t)
#pragma unroll
      for (int r = 0; r < 4; ++r)
        part[(kq * 64 + bt2 * 32 + t * 16 + q * 4 + r) * 17 + c] = acc[t][r];
  };

  // Reduce 4 K-partials, nonlin, c-state (regs), coalesced agent-scope h-store.
  auto combine = [&](float* crL, const float* __restrict__ bsrc, u16* hw) {
    if (tid < 128) {
      int b = tid >> 1, u2 = (tid & 1) * 2;
      u32 pk = 0;
#pragma unroll
      for (int e = 0; e < 2; ++e) {
        int u = u2 + e;
        float s[4];
#pragma unroll
        for (int g = 0; g < 4; ++g) {
          float sv = bsrc[g * 1024 + ng * 4 + u];
#pragma unroll
          for (int kqi = 0; kqi < 4; ++kqi)
            sv += part[(kqi * 64 + b) * 17 + g * 4 + u];
          s[g] = sv;
        }
        float iv = 1.f / (1.f + __expf(-s[0]));
        float fv = 1.f / (1.f + __expf(-s[1]));
        float gv = tanhf(s[2]);
        float ov = 1.f / (1.f + __expf(-s[3]));
        float cn = fv * crL[e] + iv * gv;
        crL[e] = cn;
        f16 hh = (f16)(ov * tanhf(cn));
        pk |= ((u32)*(u16*)&hh) << (16 * e);
      }
      // h[b][4ng+u] -> halves at (ng>>1)*512 + b*8 + (ng&1)*4 + u2
      u32* dst = (u32*)hw + (size_t)(ng >> 1) * 256 + b * 4 + (ng & 1) * 2 + (tid & 1);
      __hip_atomic_store(dst, pk, __ATOMIC_RELAXED, __HIP_MEMORY_SCOPE_AGENT);
    }
  };

  auto dec_partial = [&](const u16* __restrict__ h2b) {
    if (ng < 171) {
      const u16* hp = h2b + (size_t)w * 16 * 512 + lane * 8;
      const u16* wp = p.wdec + (size_t)ng * 1024 + w * 128;
      float s = 0.f;
#pragma unroll 4
      for (int i = 0; i < 16; ++i) {
        h8 hv = *(const h8*)(hp + (size_t)i * 512);
        h8 wv8 = *(const h8*)(wp + i * 8);
#pragma unroll
        for (int jj = 0; jj < 8; ++jj) s += (float)hv[jj] * (float)wv8[jj];
      }
      decp[w][lane] = s;
    }
  };
  auto dec_reduce = [&](int tout) {
    if (ng < 171 && tid < 64) {
      float o = p.dec_b[ng];
#pragma unroll
      for (int i = 0; i < 8; ++i) o += decp[i][tid];
      p.out[(size_t)tid * 17100 + (size_t)tout * 171 + ng] = o;
    }
  };

  for (int t = 0; t < 100; ++t) {
    const bool cond = (t % 10) < 5;
    const u16* h0r = p.h0 + (size_t)t * HSZ;  // slot 0 = zeros
    const u16* h1r = p.h1 + (size_t)t * HSZ;
    const u16* h2r = p.h2 + (size_t)t * HSZ;
    u16* h0w = p.h0 + (size_t)(t + 1) * HSZ;
    u16* h1w = p.h1 + (size_t)(t + 1) * HSZ;
    u16* h2w = p.h2 + (size_t)(t + 1) * HSZ;

    // ---- window A: layer 1 (+ decoder for t-1) ----
    {
      arrive();                                        // publish h2(t-1)
      f4 acc[2] = {{0, 0, 0, 0}, {0, 0, 0, 0}};
      gemm_hreg<8>(acc, h0r, r_w1h, kq, bt2, q, c);    // stale (3 windows old)
      if (cond) gemm_fr(acc, p.fr + (size_t)t * 64 * 192, r_w1x, kq, bt2, q, c);
      waitall();
      if (!cond) gemm_hreg<8>(acc, h2r, r_weff, kq, bt2, q, c);  // fresh
      if (t > 0) dec_partial(h2r);                     // fresh
      put_part(acc);
      __syncthreads();
      combine(cr0, cond ? p.br : p.ba, h0w);
      if (t > 0) dec_reduce(t - 1);
    }
    // ---- window B: layer 2 ----
    {
      arrive();                                        // publish h0(t)
      f4 acc[2] = {{0, 0, 0, 0}, {0, 0, 0, 0}};
      gemm_hlds(acc, h1r, lds_w2, 32, kq, bt2, q, c, lane);  // stale (hh part)
      waitall();
      gemm_hlds(acc, h0w, lds_w2, 0, kq, bt2, q, c, lane);   // fresh (ih part)
      put_part(acc);
      __syncthreads();
      combine(cr1, p.b2s, h1w);
    }
    // ---- window C: layer 3 ----
    {
      arrive();                                        // publish h1(t)
      f4 acc[2] = {{0, 0, 0, 0}, {0, 0, 0, 0}};
      gemm_hlds(acc, h2r, lds_w3, 32, kq, bt2, q, c, lane);  // stale (hh part)
      waitall();
      gemm_hlds(acc, h1w, lds_w3, 0, kq, bt2, q, c, lane);   // fresh (ih part)
      put_part(acc);
      __syncthreads();
      combine(cr2, p.b3s, h2w);
    }
  }
  // final decoder: out(99) from h2 slot 100
  arrive();
  waitall();
  dec_partial(p.h2 + (size_t)100 * HSZ);
  __syncthreads();
  dec_reduce(99);
}

// ------------------------- prep kernels -------------------------

// Pack [4096 x (KA+KB)] fp32 weights (two halves) into MFMA-B fragments:
// dst[((ng*nkt + kt)*64 + lane)*8 + j] = W[row(c)][kt*32 + (lane>>4)*8 + j]
// row(c) = (c>>2)*1024 + ng*4 + (c&3).  Zero-pads k >= KA+KB.
__global__ void pack_w_kernel(const float* __restrict__ srcA, int KA,
                              const float* __restrict__ srcB, int KB,
                              u16* __restrict__ dst, int nkt) {
  int blk = blockIdx.x;
  int ng = blk / nkt, kt = blk % nkt;
  int lane = threadIdx.x;
  int c = lane & 15, q = lane >> 4;
  int row = (c >> 2) * 1024 + ng * 4 + (c & 3);
  int k0 = kt * 32 + q * 8;
  alignas(16) u16 outv[8];
  for (int j = 0; j < 8; ++j) {
    int k = k0 + j;
    float v = 0.f;
    if (k < KA) v = srcA[(size_t)row * KA + k];
    else if (k - KA < KB) v = srcB[(size_t)row * KB + (k - KA)];
    f16 hv = (f16)v;
    outv[j] = *(u16*)&hv;
  }
  *(uint4*)(dst + ((size_t)blk * 64 + lane) * 8) = *(const uint4*)outv;
}

// W_eff[n][k] = sum_{r<171} w_ih1[n][r] * dec_w[r][k], MFMA-B packed fp16.
__global__ void pack_weff_kernel(const float* __restrict__ w_ih1,
                                 const float* __restrict__ dec_w, u16* __restrict__ dst) {
  int blk = blockIdx.x;  // ng*32 + kt
  int ng = blk >> 5, kt = blk & 31;
  int lane = threadIdx.x;
  int c = lane & 15, q = lane >> 4;
  int row = (c >> 2) * 1024 + ng * 4 + (c & 3);
  int k0 = kt * 32 + q * 8;
  float acc[8] = {0.f, 0.f, 0.f, 0.f, 0.f, 0.f, 0.f, 0.f};
  for (int r = 0; r < 171; ++r) {
    float wi = w_ih1[(size_t)row * 171 + r];
    const float* dw = dec_w + (size_t)r * 1024 + k0;
#pragma unroll
    for (int j = 0; j < 8; ++j) acc[j] += wi * dw[j];
  }
  alignas(16) u16 outv[8];
  for (int j = 0; j < 8; ++j) { f16 hv = (f16)acc[j]; outv[j] = *(u16*)&hv; }
  *(uint4*)(dst + ((size_t)blk * 64 + lane) * 8) = *(const uint4*)outv;
}

__global__ void prep_bias_kernel(const float* b_ih1, const float* b_hh1,
                                 const float* w_ih1, const float* dec_b,
                                 const float* b_ih2, const float* b_hh2,
                                 const float* b_ih3, const float* b_hh3,
                                 float* br, float* ba, float* b2, float* b3) {
  int n = blockIdx.x * 256 + threadIdx.x;  // 0..4095
  float s = b_ih1[n] + b_hh1[n];
  br[n] = s;
  float a = 0.f;
  for (int r = 0; r < 171; ++r) a += w_ih1[(size_t)n * 171 + r] * dec_b[r];
  ba[n] = s + a;  // autoregressive path: + W_ih1 @ dec_b
  b2[n] = b_ih2[n] + b_hh2[n];
  b3[n] = b_ih3[n] + b_hh3[n];
}

// real_seq [64][100][171] fp32 -> fr16 [100][64][192] fp16 (zero-padded K)
__global__ void pack_frames_kernel(const float* __restrict__ rs, u16* __restrict__ fr) {
  int i = blockIdx.x * 256 + threadIdx.x;
  int j = i % 192;
  int tb = i / 192;
  int b = tb % 64, t = tb / 64;
  float v = (j < 171) ? rs[((size_t)b * 100 + t) * 171 + j] : 0.f;
  f16 hv = (f16)v;
  fr[i] = *(u16*)&hv;
}

__global__ void pack_wdec_kernel(const float* __restrict__ dw, u16* __restrict__ dst) {
  int i = blockIdx.x * 256 + threadIdx.x;
  if (i < 171 * 1024) { f16 hv = (f16)dw[i]; dst[i] = *(u16*)&hv; }
}

// zero h slot 0 of each buffer (initial state) and the barrier page (8 KB)
__global__ void zero_kernel(u32* h0, u32* h1, u32* h2, u32* bar) {
  int i = blockIdx.x * 256 + threadIdx.x;  // 0..32767
  h0[i] = 0; h1[i] = 0; h2[i] = 0;
  if (blockIdx.x < 8) bar[i] = 0;  // 2048 u32
}

extern "C" void kernel_launch(void* const* d_in, const int* in_sizes, int n_in,
                              void* d_out, int out_size, void* d_ws, size_t ws_size,
                              hipStream_t stream) {
  const float* real_seq = (const float*)d_in[0];
  const float* w_ih1 = (const float*)d_in[1];
  const float* w_hh1 = (const float*)d_in[2];
  const float* b_ih1 = (const float*)d_in[3];
  const float* b_hh1 = (const float*)d_in[4];
  const float* w_ih2 = (const float*)d_in[5];
  const float* w_hh2 = (const float*)d_in[6];
  const float* b_ih2 = (const float*)d_in[7];
  const float* b_hh2 = (const float*)d_in[8];
  const float* w_ih3 = (const float*)d_in[9];
  const float* w_hh3 = (const float*)d_in[10];
  const float* b_ih3 = (const float*)d_in[11];
  const float* b_hh3 = (const float*)d_in[12];
  const float* dec_w = (const float*)d_in[13];
  const float* dec_b = (const float*)d_in[14];

  char* ws = (char*)d_ws;
  size_t off = 0;
  auto alloc = [&](size_t bytes) {
    char* pp = ws + off;
    off += (bytes + 255) & ~(size_t)255;
    return pp;
  };
  u16* w1h  = (u16*)alloc(256ULL * 32 * 512 * 2);   // w_hh1 packed
  u16* weff = (u16*)alloc(256ULL * 32 * 512 * 2);   // W_ih1 @ dec_w packed
  u16* w1x  = (u16*)alloc(256ULL * 6 * 512 * 2);    // w_ih1 packed (K padded 192)
  u16* w2   = (u16*)alloc(256ULL * 64 * 512 * 2);   // [w_ih2 | w_hh2] packed
  u16* w3   = (u16*)alloc(256ULL * 64 * 512 * 2);   // [w_ih3 | w_hh3] packed
  u16* wdec = (u16*)alloc(171ULL * 1024 * 2);       // dec_w fp16 row-major
  u16* fr   = (u16*)alloc(100ULL * 64 * 192 * 2);   // frames fp16 padded
  u16* h0   = (u16*)alloc(101ULL * HSZ * 2);        // rotating h, [k/8][b][8]
  u16* h1   = (u16*)alloc(101ULL * HSZ * 2);
  u16* h2   = (u16*)alloc(101ULL * HSZ * 2);
  float* br  = (float*)alloc(4096 * 4);
  float* ba  = (float*)alloc(4096 * 4);
  float* b2s = (float*)alloc(4096 * 4);
  float* b3s = (float*)alloc(4096 * 4);
  u32* bar   = (u32*)alloc(8192);
  (void)ws_size; (void)in_sizes; (void)n_in; (void)out_size;  // needs ~91 MiB ws

  pack_w_kernel<<<256 * 32, 64, 0, stream>>>(w_hh1, 1024, nullptr, 0, w1h, 32);
  pack_w_kernel<<<256 * 6, 64, 0, stream>>>(w_ih1, 171, nullptr, 0, w1x, 6);
  pack_w_kernel<<<256 * 64, 64, 0, stream>>>(w_ih2, 1024, w_hh2, 1024, w2, 64);
  pack_w_kernel<<<256 * 64, 64, 0, stream>>>(w_ih3, 1024, w_hh3, 1024, w3, 64);
  pack_weff_kernel<<<256 * 32, 64, 0, stream>>>(w_ih1, dec_w, weff);
  pack_wdec_kernel<<<(171 * 1024 + 255) / 256, 256, 0, stream>>>(dec_w, wdec);
  pack_frames_kernel<<<100 * 64 * 192 / 256, 256, 0, stream>>>(real_seq, fr);
  prep_bias_kernel<<<16, 256, 0, stream>>>(b_ih1, b_hh1, w_ih1, dec_b,
                                           b_ih2, b_hh2, b_ih3, b_hh3, br, ba, b2s, b3s);
  zero_kernel<<<128, 256, 0, stream>>>((u32*)h0, (u32*)h1, (u32*)h2, bar);

  P p{w1h, weff, w1x, w2, w3, wdec, fr, br, ba, b2s, b3s, dec_b,
      h0, h1, h2, (float*)d_out, bar};
  lstm_main<<<256, 512, 0, stream>>>(p);
}

// Round 5
// 2030.888 us; speedup vs baseline: 3.1462x; 1.0493x over previous
//
#include <hip/hip_runtime.h>
#include <hip/hip_fp16.h>

// Persistent-kernel autoregressive LSTM for MI355X (gfx950).  Round 5.
//
// R4 post-mortem: both barrier designs gave identical 6.3us windows -> the
// cost is the serial producer->consumer chain (rendezvous + combine + drain +
// detect + fresh-read), not barrier mechanics. R5: (1) wave-local publish --
// wave 0 alone computes gates/c-state/h for all 64 batch rows, drains its own
// vmcnt, stores the slot; no WG rendezvous between gate math and publish;
// (2) cond window-A skips the grid wait entirely (no fresh operand);
// (3) decoder runs in window C where h2(t-1) is certified-stale;
// (4) register-hoisted biases + __expf-based sigmoid/tanh in combine.

typedef unsigned short u16;
typedef unsigned int u32;
typedef _Float16 f16;
typedef _Float16 h8 __attribute__((ext_vector_type(8)));
typedef float f4 __attribute__((ext_vector_type(4)));

#define HSZ 65536  // halves per h slot: layout [128 kgrp][64 b][8 u]

static __device__ __forceinline__ f4 mfma16(h8 a, h8 b, f4 c) {
  return __builtin_amdgcn_mfma_f32_16x16x32_f16(a, b, c, 0, 0, 0);
}

static __device__ __forceinline__ float fsig(float x) {
  return 1.f / (1.f + __expf(-x));
}
// overflow-safe: x->+inf => 1, x->-inf => -1 (no inf/inf NaN)
static __device__ __forceinline__ float ftanh(float x) {
  return 1.f - 2.f / (1.f + __expf(2.f * x));
}

struct P {
  const u16 *w1h, *weff, *w1x, *w2, *w3, *wdec, *fr;
  const float *br, *ba, *b2s, *b3s, *dec_b;
  u16 *h0, *h1, *h2;
  float* out;
  u32* bar;
};

// A-frag (16x32 tile): lane(q=lane>>4, c=lane&15) holds A[m=c][k=q*8+j].
// h element [b][k] lives at [(k>>3)*512 + b*8 + (k&7)] -> one h8 load.
// Wave (kq, bt2) covers K-quarter kq (8 kt) x batch rows [bt2*32, bt2*32+32).
template<int NJ>
static __device__ __forceinline__ void gemm_hreg(f4* acc, const u16* __restrict__ h,
                                                 const h8 (&wr)[NJ], int kq, int bt2,
                                                 int q, int c) {
#pragma unroll
  for (int jj = 0; jj < NJ; ++jj) {
    int kt = kq * 8 + jj;
    const u16* hp = h + (size_t)(kt * 4 + q) * 512;
    h8 b = wr[jj];
#pragma unroll
    for (int t = 0; t < 2; ++t) {
      h8 a = *(const h8*)(hp + ((bt2 * 2 + t) * 16 + c) * 8);
      acc[t] = mfma16(a, b, acc[t]);
    }
  }
}

// Same, weights from LDS (w2/w3), kt offset by ktbase.
static __device__ __forceinline__ void gemm_hlds(f4* acc, const u16* __restrict__ h,
                                                 const u16* lw, int ktbase, int kq,
                                                 int bt2, int q, int c, int lane) {
#pragma unroll
  for (int jj = 0; jj < 8; ++jj) {
    int kt = kq * 8 + jj;
    h8 b = *(const h8*)(lw + (size_t)((ktbase + kt) * 64 + lane) * 8);
    const u16* hp = h + (size_t)(kt * 4 + q) * 512;
#pragma unroll
    for (int t = 0; t < 2; ++t) {
      h8 a = *(const h8*)(hp + ((bt2 * 2 + t) * 16 + c) * 8);
      acc[t] = mfma16(a, b, acc[t]);
    }
  }
}

// Frame input [64][192] row-major; kt in [0,6) mapped kt = kq*2+jj, kq<3.
static __device__ __forceinline__ void gemm_fr(f4* acc, const u16* __restrict__ frt,
                                               const h8 (&wr)[2], int kq, int bt2,
                                               int q, int c) {
  if (kq < 3) {
#pragma unroll
    for (int jj = 0; jj < 2; ++jj) {
      int kt = kq * 2 + jj;
      h8 b = wr[jj];
#pragma unroll
      for (int t = 0; t < 2; ++t) {
        h8 a = *(const h8*)(frt + (size_t)((bt2 * 2 + t) * 16 + c) * 192 + kt * 32 + q * 8);
        acc[t] = mfma16(a, b, acc[t]);
      }
    }
  }
}

__launch_bounds__(512, 2)
__global__ void lstm_main(P p) {
  const int ng = blockIdx.x;        // unit-group: owns hidden units [4ng, 4ng+4)
  const int tid = threadIdx.x;
  const int lane = tid & 63;
  const int w = tid >> 6;           // 8 waves
  const int kq = w & 3;             // K-quarter
  const int bt2 = w >> 2;           // batch half
  const int c = lane & 15;
  const int q = lane >> 4;

  __shared__ u16 lds_w2[64 * 512];       // 64 KB  [kt][lane][8] B-frags
  __shared__ u16 lds_w3[64 * 512];       // 64 KB
  __shared__ float part[4 * 64 * 17];    // [kq][brow][c pad17]
  __shared__ float decp[8][64];

  // ---- one-time: stage w2/w3 slices into LDS ----
  {
    const uint4* s2 = (const uint4*)(p.w2 + (size_t)ng * 64 * 512);
    const uint4* s3 = (const uint4*)(p.w3 + (size_t)ng * 64 * 512);
    uint4* d2 = (uint4*)lds_w2;
    uint4* d3 = (uint4*)lds_w3;
    for (int i = tid; i < 4096; i += 512) { d2[i] = s2[i]; d3[i] = s3[i]; }
  }

  // ---- one-time: w1h/weff/w1x B-frags into registers (~72 VGPR/wave) ----
  h8 r_w1h[8], r_weff[8], r_w1x[2];
  {
#pragma unroll
    for (int jj = 0; jj < 8; ++jj) {
      r_w1h[jj] = *(const h8*)(p.w1h + (size_t)((ng * 32 + kq * 8 + jj) * 64 + lane) * 8);
      r_weff[jj] = *(const h8*)(p.weff + (size_t)((ng * 32 + kq * 8 + jj) * 64 + lane) * 8);
    }
    if (kq < 3) {
#pragma unroll
      for (int jj = 0; jj < 2; ++jj)
        r_w1x[jj] = *(const h8*)(p.w1x + (size_t)((ng * 6 + kq * 2 + jj) * 64 + lane) * 8);
    }
  }

  // ---- wave-0-only: hoist the 4x16 bias vectors into registers ----
  float rb_r[16], rb_a[16], rb2[16], rb3[16];
  if (w == 0) {
#pragma unroll
    for (int i = 0; i < 16; ++i) {
      int idx = (i >> 2) * 1024 + ng * 4 + (i & 3);
      rb_r[i] = p.br[idx];  rb_a[i] = p.ba[idx];
      rb2[i] = p.b2s[idx];  rb3[i] = p.b3s[idx];
    }
  }
  const float dec_bng = (ng < 171) ? p.dec_b[ng] : 0.f;
  __syncthreads();

  // c-state: wave 0, lane = batch row, 4 units per layer
  float cr0[4] = {0, 0, 0, 0}, cr1[4] = {0, 0, 0, 0}, cr2[4] = {0, 0, 0, 0};
  u32 pub = 0;  // publishes completed (uniform across all threads)

  // wave 0 only: reduce K-partials, nonlin, c-state, h-store, drain, publish.
  auto combine_pub = [&](float* crL, const float* rb, u16* hw) {
    u32 pk0 = 0, pk1 = 0;
#pragma unroll
    for (int u = 0; u < 4; ++u) {
      float s0 = rb[0 + u], s1 = rb[4 + u], s2 = rb[8 + u], s3 = rb[12 + u];
#pragma unroll
      for (int kqi = 0; kqi < 4; ++kqi) {
        const float* pp = &part[(kqi * 64 + lane) * 17 + u];
        s0 += pp[0]; s1 += pp[4]; s2 += pp[8]; s3 += pp[12];
      }
      float iv = fsig(s0), fv = fsig(s1), gv = ftanh(s2), ov = fsig(s3);
      float cn = fv * crL[u] + iv * gv;
      crL[u] = cn;
      f16 hh = (f16)(ov * ftanh(cn));
      u32 bits = (u32)*(const u16*)&hh;
      if (u < 2) pk0 |= bits << (16 * u); else pk1 |= bits << (16 * (u - 2));
    }
    // h[b][4ng+u]: u32 base (ng>>1)*256 + b*4 + (ng&1)*2
    u32* dst = (u32*)hw + (size_t)(ng >> 1) * 256 + lane * 4 + (ng & 1) * 2;
    __hip_atomic_store(dst, pk0, __ATOMIC_RELAXED, __HIP_MEMORY_SCOPE_AGENT);
    __hip_atomic_store(dst + 1, pk1, __ATOMIC_RELAXED, __HIP_MEMORY_SCOPE_AGENT);
    __builtin_amdgcn_s_waitcnt(0x0f70);  // vmcnt(0): h globally visible first
    if (lane == 0)
      __hip_atomic_store(p.bar + ng, pub, __ATOMIC_RELAXED, __HIP_MEMORY_SCOPE_AGENT);
  };

  // wave 0 polls all 256 slots for >= pub; other waves park at the barrier.
  auto waitall = [&]() {
    if (w == 0) {
      for (;;) {
        u32 v0 = __hip_atomic_load(p.bar + lane, __ATOMIC_RELAXED, __HIP_MEMORY_SCOPE_AGENT);
        u32 v1 = __hip_atomic_load(p.bar + 64 + lane, __ATOMIC_RELAXED, __HIP_MEMORY_SCOPE_AGENT);
        u32 v2 = __hip_atomic_load(p.bar + 128 + lane, __ATOMIC_RELAXED, __HIP_MEMORY_SCOPE_AGENT);
        u32 v3 = __hip_atomic_load(p.bar + 192 + lane, __ATOMIC_RELAXED, __HIP_MEMORY_SCOPE_AGENT);
        u32 m01 = v0 < v1 ? v0 : v1;
        u32 m23 = v2 < v3 ? v2 : v3;
        u32 mn = m01 < m23 ? m01 : m23;
        if (__all((int)(mn >= pub))) break;
      }
    }
    __syncthreads();
  };

  auto put_part = [&](const f4* acc) {
#pragma unroll
    for (int t = 0; t < 2; ++t)
#pragma unroll
      for (int r = 0; r < 4; ++r)
        part[(kq * 64 + bt2 * 32 + t * 16 + q * 4 + r) * 17 + c] = acc[t][r];
  };

  auto dec_partial = [&](const u16* __restrict__ h2b) {
    if (ng < 171) {
      const u16* hp = h2b + (size_t)w * 16 * 512 + lane * 8;
      const u16* wp = p.wdec + (size_t)ng * 1024 + w * 128;
      float s = 0.f;
#pragma unroll 4
      for (int i = 0; i < 16; ++i) {
        h8 hv = *(const h8*)(hp + (size_t)i * 512);
        h8 wv8 = *(const h8*)(wp + i * 8);
#pragma unroll
        for (int jj = 0; jj < 8; ++jj) s += (float)hv[jj] * (float)wv8[jj];
      }
      decp[w][lane] = s;
    }
  };
  auto dec_reduce = [&](int tout) {  // one wave, lane = batch row
    if (ng < 171) {
      float o = dec_bng;
#pragma unroll
      for (int i = 0; i < 8; ++i) o += decp[i][lane];
      p.out[(size_t)lane * 17100 + (size_t)tout * 171 + ng] = o;
    }
  };

  for (int t = 0; t < 100; ++t) {
    const bool cond = (t % 10) < 5;
    const u16* h0r = p.h0 + (size_t)t * HSZ;  // slot 0 = zeros
    const u16* h1r = p.h1 + (size_t)t * HSZ;
    const u16* h2r = p.h2 + (size_t)t * HSZ;
    u16* h0w = p.h0 + (size_t)(t + 1) * HSZ;
    u16* h1w = p.h1 + (size_t)(t + 1) * HSZ;
    u16* h2w = p.h2 + (size_t)(t + 1) * HSZ;

    // ---- window A: layer 1 ----
    {
      f4 acc[2] = {{0, 0, 0, 0}, {0, 0, 0, 0}};
      gemm_hreg<8>(acc, h0r, r_w1h, kq, bt2, q, c);   // stale (certified)
      if (cond) {
        gemm_fr(acc, p.fr + (size_t)t * 64 * 192, r_w1x, kq, bt2, q, c);
        __syncthreads();   // rendezvous only: no fresh operand, skip grid wait
      } else {
        waitall();                                    // h2(t-1) publishes
        gemm_hreg<8>(acc, h2r, r_weff, kq, bt2, q, c);
      }
      put_part(acc);
      __syncthreads();
      ++pub;
      if (w == 0) combine_pub(cr0, cond ? rb_r : rb_a, h0w);
    }
    // ---- window B: layer 2 ----
    {
      f4 acc[2] = {{0, 0, 0, 0}, {0, 0, 0, 0}};
      gemm_hlds(acc, h1r, lds_w2, 32, kq, bt2, q, c, lane);  // stale hh-half
      waitall();                                             // h0(t) publishes
      gemm_hlds(acc, h0w, lds_w2, 0, kq, bt2, q, c, lane);   // fresh ih-half
      put_part(acc);
      __syncthreads();
      ++pub;
      if (w == 0) combine_pub(cr1, rb2, h1w);
    }
    // ---- window C: layer 3 (+ decoder for t-1, stale h2) ----
    {
      f4 acc[2] = {{0, 0, 0, 0}, {0, 0, 0, 0}};
      gemm_hlds(acc, h2r, lds_w3, 32, kq, bt2, q, c, lane);  // stale hh-half
      if (t > 0) dec_partial(h2r);                           // stale (certified)
      waitall();                                             // h1(t) publishes
      gemm_hlds(acc, h1w, lds_w3, 0, kq, bt2, q, c, lane);   // fresh ih-half
      put_part(acc);
      __syncthreads();
      ++pub;
      if (w == 0) combine_pub(cr2, rb3, h2w);
      else if (w == 1 && t > 0) dec_reduce(t - 1);
    }
  }
  // final decoder: out(99) from h2 slot 100
  waitall();
  dec_partial(p.h2 + (size_t)100 * HSZ);
  __syncthreads();
  if (w == 0) dec_reduce(99);
}

// ------------------------- prep kernels -------------------------

// Pack [4096 x (KA+KB)] fp32 weights (two halves) into MFMA-B fragments:
// dst[((ng*nkt + kt)*64 + lane)*8 + j] = W[row(c)][kt*32 + (lane>>4)*8 + j]
// row(c) = (c>>2)*1024 + ng*4 + (c&3).  Zero-pads k >= KA+KB.
__global__ void pack_w_kernel(const float* __restrict__ srcA, int KA,
                              const float* __restrict__ srcB, int KB,
                              u16* __restrict__ dst, int nkt) {
  int blk = blockIdx.x;
  int ng = blk / nkt, kt = blk % nkt;
  int lane = threadIdx.x;
  int c = lane & 15, q = lane >> 4;
  int row = (c >> 2) * 1024 + ng * 4 + (c & 3);
  int k0 = kt * 32 + q * 8;
  alignas(16) u16 outv[8];
  for (int j = 0; j < 8; ++j) {
    int k = k0 + j;
    float v = 0.f;
    if (k < KA) v = srcA[(size_t)row * KA + k];
    else if (k - KA < KB) v = srcB[(size_t)row * KB + (k - KA)];
    f16 hv = (f16)v;
    outv[j] = *(u16*)&hv;
  }
  *(uint4*)(dst + ((size_t)blk * 64 + lane) * 8) = *(const uint4*)outv;
}

// W_eff[n][k] = sum_{r<171} w_ih1[n][r] * dec_w[r][k], MFMA-B packed fp16.
__global__ void pack_weff_kernel(const float* __restrict__ w_ih1,
                                 const float* __restrict__ dec_w, u16* __restrict__ dst) {
  int blk = blockIdx.x;  // ng*32 + kt
  int ng = blk >> 5, kt = blk & 31;
  int lane = threadIdx.x;
  int c = lane & 15, q = lane >> 4;
  int row = (c >> 2) * 1024 + ng * 4 + (c & 3);
  int k0 = kt * 32 + q * 8;
  float acc[8] = {0.f, 0.f, 0.f, 0.f, 0.f, 0.f, 0.f, 0.f};
  for (int r = 0; r < 171; ++r) {
    float wi = w_ih1[(size_t)row * 171 + r];
    const float* dw = dec_w + (size_t)r * 1024 + k0;
#pragma unroll
    for (int j = 0; j < 8; ++j) acc[j] += wi * dw[j];
  }
  alignas(16) u16 outv[8];
  for (int j = 0; j < 8; ++j) { f16 hv = (f16)acc[j]; outv[j] = *(u16*)&hv; }
  *(uint4*)(dst + ((size_t)blk * 64 + lane) * 8) = *(const uint4*)outv;
}

__global__ void prep_bias_kernel(const float* b_ih1, const float* b_hh1,
                                 const float* w_ih1, const float* dec_b,
                                 const float* b_ih2, const float* b_hh2,
                                 const float* b_ih3, const float* b_hh3,
                                 float* br, float* ba, float* b2, float* b3) {
  int n = blockIdx.x * 256 + threadIdx.x;  // 0..4095
  float s = b_ih1[n] + b_hh1[n];
  br[n] = s;
  float a = 0.f;
  for (int r = 0; r < 171; ++r) a += w_ih1[(size_t)n * 171 + r] * dec_b[r];
  ba[n] = s + a;  // autoregressive path: + W_ih1 @ dec_b
  b2[n] = b_ih2[n] + b_hh2[n];
  b3[n] = b_ih3[n] + b_hh3[n];
}

// real_seq [64][100][171] fp32 -> fr16 [100][64][192] fp16 (zero-padded K)
__global__ void pack_frames_kernel(const float* __restrict__ rs, u16* __restrict__ fr) {
  int i = blockIdx.x * 256 + threadIdx.x;
  int j = i % 192;
  int tb = i / 192;
  int b = tb % 64, t = tb / 64;
  float v = (j < 171) ? rs[((size_t)b * 100 + t) * 171 + j] : 0.f;
  f16 hv = (f16)v;
  fr[i] = *(u16*)&hv;
}

__global__ void pack_wdec_kernel(const float* __restrict__ dw, u16* __restrict__ dst) {
  int i = blockIdx.x * 256 + threadIdx.x;
  if (i < 171 * 1024) { f16 hv = (f16)dw[i]; dst[i] = *(u16*)&hv; }
}

// zero h slot 0 of each buffer (initial state) and the barrier page (8 KB)
__global__ void zero_kernel(u32* h0, u32* h1, u32* h2, u32* bar) {
  int i = blockIdx.x * 256 + threadIdx.x;  // 0..32767
  h0[i] = 0; h1[i] = 0; h2[i] = 0;
  if (blockIdx.x < 8) bar[i] = 0;  // 2048 u32
}

extern "C" void kernel_launch(void* const* d_in, const int* in_sizes, int n_in,
                              void* d_out, int out_size, void* d_ws, size_t ws_size,
                              hipStream_t stream) {
  const float* real_seq = (const float*)d_in[0];
  const float* w_ih1 = (const float*)d_in[1];
  const float* w_hh1 = (const float*)d_in[2];
  const float* b_ih1 = (const float*)d_in[3];
  const float* b_hh1 = (const float*)d_in[4];
  const float* w_ih2 = (const float*)d_in[5];
  const float* w_hh2 = (const float*)d_in[6];
  const float* b_ih2 = (const float*)d_in[7];
  const float* b_hh2 = (const float*)d_in[8];
  const float* w_ih3 = (const float*)d_in[9];
  const float* w_hh3 = (const float*)d_in[10];
  const float* b_ih3 = (const float*)d_in[11];
  const float* b_hh3 = (const float*)d_in[12];
  const float* dec_w = (const float*)d_in[13];
  const float* dec_b = (const float*)d_in[14];

  char* ws = (char*)d_ws;
  size_t off = 0;
  auto alloc = [&](size_t bytes) {
    char* pp = ws + off;
    off += (bytes + 255) & ~(size_t)255;
    return pp;
  };
  u16* w1h  = (u16*)alloc(256ULL * 32 * 512 * 2);   // w_hh1 packed
  u16* weff = (u16*)alloc(256ULL * 32 * 512 * 2);   // W_ih1 @ dec_w packed
  u16* w1x  = (u16*)alloc(256ULL * 6 * 512 * 2);    // w_ih1 packed (K padded 192)
  u16* w2   = (u16*)alloc(256ULL * 64 * 512 * 2);   // [w_ih2 | w_hh2] packed
  u16* w3   = (u16*)alloc(256ULL * 64 * 512 * 2);   // [w_ih3 | w_hh3] packed
  u16* wdec = (u16*)alloc(171ULL * 1024 * 2);       // dec_w fp16 row-major
  u16* fr   = (u16*)alloc(100ULL * 64 * 192 * 2);   // frames fp16 padded
  u16* h0   = (u16*)alloc(101ULL * HSZ * 2);        // rotating h, [k/8][b][8]
  u16* h1   = (u16*)alloc(101ULL * HSZ * 2);
  u16* h2   = (u16*)alloc(101ULL * HSZ * 2);
  float* br  = (float*)alloc(4096 * 4);
  float* ba  = (float*)alloc(4096 * 4);
  float* b2s = (float*)alloc(4096 * 4);
  float* b3s = (float*)alloc(4096 * 4);
  u32* bar   = (u32*)alloc(8192);
  (void)ws_size; (void)in_sizes; (void)n_in; (void)out_size;  // needs ~91 MiB ws

  pack_w_kernel<<<256 * 32, 64, 0, stream>>>(w_hh1, 1024, nullptr, 0, w1h, 32);
  pack_w_kernel<<<256 * 6, 64, 0, stream>>>(w_ih1, 171, nullptr, 0, w1x, 6);
  pack_w_kernel<<<256 * 64, 64, 0, stream>>>(w_ih2, 1024, w_hh2, 1024, w2, 64);
  pack_w_kernel<<<256 * 64, 64, 0, stream>>>(w_ih3, 1024, w_hh3, 1024, w3, 64);
  pack_weff_kernel<<<256 * 32, 64, 0, stream>>>(w_ih1, dec_w, weff);
  pack_wdec_kernel<<<(171 * 1024 + 255) / 256, 256, 0, stream>>>(dec_w, wdec);
  pack_frames_kernel<<<100 * 64 * 192 / 256, 256, 0, stream>>>(real_seq, fr);
  prep_bias_kernel<<<16, 256, 0, stream>>>(b_ih1, b_hh1, w_ih1, dec_b,
                                           b_ih2, b_hh2, b_ih3, b_hh3, br, ba, b2s, b3s);
  zero_kernel<<<128, 256, 0, stream>>>((u32*)h0, (u32*)h1, (u32*)h2, bar);

  P p{w1h, weff, w1x, w2, w3, wdec, fr, br, ba, b2s, b3s, dec_b,
      h0, h1, h2, (float*)d_out, bar};
  lstm_main<<<256, 512, 0, stream>>>(p);
}